// Round 7
// baseline (1085.002 us; speedup 1.0000x reference)
//
#include <hip/hip_runtime.h>
#include <math.h>
#include <stdint.h>

typedef __attribute__((ext_vector_type(8))) _Float16 f16x8;  // 8 f16 = 4 VGPR
typedef __attribute__((ext_vector_type(4))) _Float16 f16x4;  // 8 bytes
typedef __attribute__((ext_vector_type(4))) float f32x4;

// Dekker-style split: x ~= hi + lo/2048, both f16, lo kept out of denormal range.
__device__ __forceinline__ void split_f16(float x, _Float16& h, _Float16& l) {
  h = (_Float16)x;
  l = (_Float16)((x - (float)h) * 2048.0f);
}

__device__ __forceinline__ void gld16(const void* g, void* l) {
  __builtin_amdgcn_global_load_lds(
      (const __attribute__((address_space(1))) void*)g,
      (__attribute__((address_space(3))) void*)l, 16, 0, 0);
}

// ---------------- JAX threefry2x32 (key = [0,42]) + normal transform ----------------
__device__ __forceinline__ void threefry2x32_42(uint32_t x0, uint32_t x1,
                                                uint32_t& o0, uint32_t& o1) {
  const uint32_t k0 = 0u, k1 = 42u;
  const uint32_t k2 = k0 ^ k1 ^ 0x1BD11BDAu;
  x0 += k0; x1 += k1;
#define TF_R(r) { x0 += x1; x1 = (x1 << (r)) | (x1 >> (32 - (r))); x1 ^= x0; }
  TF_R(13) TF_R(15) TF_R(26) TF_R(6)
  x0 += k1; x1 += k2 + 1u;
  TF_R(17) TF_R(29) TF_R(16) TF_R(24)
  x0 += k2; x1 += k0 + 2u;
  TF_R(13) TF_R(15) TF_R(26) TF_R(6)
  x0 += k0; x1 += k1 + 3u;
  TF_R(17) TF_R(29) TF_R(16) TF_R(24)
  x0 += k1; x1 += k2 + 4u;
  TF_R(13) TF_R(15) TF_R(26) TF_R(6)
  x0 += k2; x1 += k0 + 5u;
#undef TF_R
  o0 = x0; o1 = x1;
}

__device__ __forceinline__ float jax_erfinv_f32(float x) {
  float xx = __fmul_rn(x, x);
  float w = -log1pf(-xx);
  float p;
  if (w < 5.0f) {
    w = __fadd_rn(w, -2.5f);
    p = 2.81022636e-08f;
    p = __fadd_rn(3.43273939e-07f, __fmul_rn(p, w));
    p = __fadd_rn(-3.5233877e-06f, __fmul_rn(p, w));
    p = __fadd_rn(-4.39150654e-06f, __fmul_rn(p, w));
    p = __fadd_rn(0.00021858087f, __fmul_rn(p, w));
    p = __fadd_rn(-0.00125372503f, __fmul_rn(p, w));
    p = __fadd_rn(-0.00417768164f, __fmul_rn(p, w));
    p = __fadd_rn(0.246640727f, __fmul_rn(p, w));
    p = __fadd_rn(1.50140941f, __fmul_rn(p, w));
  } else {
    w = __fadd_rn(sqrtf(w), -3.0f);
    p = -0.000200214257f;
    p = __fadd_rn(0.000100950558f, __fmul_rn(p, w));
    p = __fadd_rn(0.00134934322f, __fmul_rn(p, w));
    p = __fadd_rn(-0.00367342844f, __fmul_rn(p, w));
    p = __fadd_rn(0.00573950773f, __fmul_rn(p, w));
    p = __fadd_rn(-0.0076224613f, __fmul_rn(p, w));
    p = __fadd_rn(0.00943887047f, __fmul_rn(p, w));
    p = __fadd_rn(1.00167406f, __fmul_rn(p, w));
    p = __fadd_rn(2.83297682f, __fmul_rn(p, w));
  }
  return __fmul_rn(p, x);
}

__device__ __forceinline__ float jax_noise(uint32_t n) {
  uint32_t o0, o1;
  threefry2x32_42(0u, n, o0, o1);
  uint32_t bits = o0 ^ o1;
  uint32_t fb = (bits >> 9) | 0x3F800000u;
  float f = __fadd_rn(__uint_as_float(fb), -1.0f);
  const float lo = __uint_as_float(0xBF7FFFFFu);
  float u = __fadd_rn(__fmul_rn(f, 2.0f), lo);
  u = fmaxf(lo, u);
  return __fmul_rn(__uint_as_float(0x3FB504F3u), jax_erfinv_f32(u));
}

// ---------------- block reduction helper (256 threads = 4 waves) ----------------
__device__ __forceinline__ float block_sum_256(float v, float* buf) {
  #pragma unroll
  for (int off = 32; off > 0; off >>= 1) v += __shfl_down(v, off, 64);
  int lane = threadIdx.x & 63;
  int w = threadIdx.x >> 6;
  if (lane == 0) buf[w] = v;
  __syncthreads();
  return buf[0] + buf[1] + buf[2] + buf[3];
}

// ---------------- kernel 0: weight transpose + split ----------------
__global__ __launch_bounds__(128) void k_wsplit(
    const float* __restrict__ Wq, const float* __restrict__ Wk,
    const float* __restrict__ Wv, const float* __restrict__ Wo,
    _Float16* __restrict__ wqt_h, _Float16* __restrict__ wqt_l,
    _Float16* __restrict__ wot_h, _Float16* __restrict__ wot_l) {
  int z = blockIdx.x, tid = threadIdx.x;
  const float* src;
  int ldn, n;
  _Float16 *dh, *dl;
  if (z < 24) {
    int which = z >> 3, h = z & 7;
    src = ((which == 0) ? Wq : (which == 1) ? Wk : Wv) + (size_t)h * 1024 * 128;
    ldn = 128; n = tid;
    dh = wqt_h + (size_t)z * 128 * 1024 + (size_t)n * 1024;
    dl = wqt_l + (size_t)z * 128 * 1024 + (size_t)n * 1024;
  } else {
    int zz = z - 24;
    src = Wo; ldn = 1024; n = zz * 128 + tid;
    dh = wot_h + (size_t)n * 1024;
    dl = wot_l + (size_t)n * 1024;
  }
  for (int k0 = 0; k0 < 1024; k0 += 16) {
    f16x8 hv0, hv1, lv0, lv1;
    #pragma unroll
    for (int j = 0; j < 8; ++j) {
      _Float16 hh, ll;
      split_f16(src[(size_t)(k0 + j) * ldn + n], hh, ll);
      hv0[j] = hh; lv0[j] = ll;
    }
    #pragma unroll
    for (int j = 0; j < 8; ++j) {
      _Float16 hh, ll;
      split_f16(src[(size_t)(k0 + 8 + j) * ldn + n], hh, ll);
      hv1[j] = hh; lv1[j] = ll;
    }
    *(f16x8*)(dh + k0) = hv0; *(f16x8*)(dh + k0 + 8) = hv1;
    *(f16x8*)(dl + k0) = lv0; *(f16x8*)(dl + k0 + 8) = lv1;
  }
}

// ---------------- kernel 1: embed + LN1 (xn written as hi/lo f16 planes) ----------------
__global__ __launch_bounds__(256) void k_embed_ln1(
    const int* __restrict__ idx, const float* __restrict__ tok,
    const float* __restrict__ pos, const float* __restrict__ g1,
    const float* __restrict__ b1, float* __restrict__ x_out,
    _Float16* __restrict__ xnh, _Float16* __restrict__ xnl) {
  __shared__ float bufA[4], bufB[4];
  int r = blockIdx.x;
  int t = r & 2047;
  int token = idx[r];
  int c4 = threadIdx.x;
  float4 tv = *((const float4*)(tok + (size_t)token * 1024) + c4);
  float4 pv = *((const float4*)(pos + (size_t)t * 1024) + c4);
  float4 xv = make_float4(tv.x + pv.x, tv.y + pv.y, tv.z + pv.z, tv.w + pv.w);
  *((float4*)(x_out + (size_t)r * 1024) + c4) = xv;
  float mu = block_sum_256(xv.x + xv.y + xv.z + xv.w, bufA) * (1.0f / 1024.0f);
  float d0 = xv.x - mu, d1 = xv.y - mu, d2 = xv.z - mu, d3 = xv.w - mu;
  float var = block_sum_256(d0*d0 + d1*d1 + d2*d2 + d3*d3, bufB) * (1.0f / 1024.0f);
  float rs = rsqrtf(var + 1e-5f);
  float4 gv = *((const float4*)g1 + c4);
  float4 bv = *((const float4*)b1 + c4);
  float xn0 = d0*rs*gv.x + bv.x, xn1 = d1*rs*gv.y + bv.y;
  float xn2 = d2*rs*gv.z + bv.z, xn3 = d3*rs*gv.w + bv.w;
  f16x4 hv, lv;
  _Float16 hh, ll;
  split_f16(xn0, hh, ll); hv[0] = hh; lv[0] = ll;
  split_f16(xn1, hh, ll); hv[1] = hh; lv[1] = ll;
  split_f16(xn2, hh, ll); hv[2] = hh; lv[2] = ll;
  split_f16(xn3, hh, ll); hv[3] = hh; lv[3] = ll;
  *(f16x4*)(xnh + (size_t)r * 1024 + c4 * 4) = hv;
  *(f16x4*)(xnl + (size_t)r * 1024 + c4 * 4) = lv;
}

// ---------------- kernel 5: LN2 ----------------
__global__ __launch_bounds__(256) void k_ln2(
    const float* __restrict__ x, const float* __restrict__ g2,
    const float* __restrict__ b2, float* __restrict__ xn_out) {
  __shared__ float bufA[4], bufB[4];
  int r = blockIdx.x;
  int c4 = threadIdx.x;
  float4 xv = *((const float4*)(x + (size_t)r * 1024) + c4);
  float mu = block_sum_256(xv.x + xv.y + xv.z + xv.w, bufA) * (1.0f / 1024.0f);
  float d0 = xv.x - mu, d1 = xv.y - mu, d2 = xv.z - mu, d3 = xv.w - mu;
  float var = block_sum_256(d0*d0 + d1*d1 + d2*d2 + d3*d3, bufB) * (1.0f / 1024.0f);
  float rs = rsqrtf(var + 1e-5f);
  float4 gv = *((const float4*)g2 + c4);
  float4 bv = *((const float4*)b2 + c4);
  float4 xn = make_float4(d0*rs*gv.x + bv.x, d1*rs*gv.y + bv.y,
                          d2*rs*gv.z + bv.z, d3*rs*gv.w + bv.w);
  *((float4*)(xn_out + (size_t)r * 1024) + c4) = xn;
}

// ---------------- kernel 2: QKV projection, double-f16 MFMA GEMM ----------------
// KSTEP=32: LDS 32KB -> high residency. grid (24, 64). 4 waves, 32 rows each.
__global__ __launch_bounds__(256) void k_qkv(
    const _Float16* __restrict__ xnh, const _Float16* __restrict__ xnl,
    const _Float16* __restrict__ wth, const _Float16* __restrict__ wtl,
    _Float16* __restrict__ qh, _Float16* __restrict__ ql,
    _Float16* __restrict__ kh, _Float16* __restrict__ kl,
    _Float16* __restrict__ vth, _Float16* __restrict__ vtl) {
  __shared__ __align__(16) _Float16 Ah[128 * 32], Al[128 * 32];  // 16 KB
  __shared__ __align__(16) _Float16 Bh[128 * 32], Bl[128 * 32];  // 16 KB
  int z = blockIdx.x;
  int which = z >> 3, h = z & 7;
  int m0 = blockIdx.y * 128;
  int tid = threadIdx.x, w = tid >> 6, lane = tid & 63;
  const _Float16* bsh = wth + (size_t)z * 128 * 1024;
  const _Float16* bsl = wtl + (size_t)z * 128 * 1024;
  f32x4 om[2][8], oc[2][8];
  const f32x4 zero4 = {0.f, 0.f, 0.f, 0.f};
  #pragma unroll
  for (int mr = 0; mr < 2; ++mr)
    #pragma unroll
    for (int nb = 0; nb < 8; ++nb) { om[mr][nb] = zero4; oc[mr][nb] = zero4; }

  for (int k0 = 0; k0 < 1024; k0 += 32) {
    __syncthreads();
    // wave w stages rows w*32..w*32+31 of A and B tiles (16 rows / inst)
    #pragma unroll
    for (int i2 = 0; i2 < 2; ++i2) {
      int r = w * 32 + i2 * 16 + (lane >> 2);
      int gs = (lane & 3) ^ ((r >> 1) & 3);
      size_t ao = (size_t)(m0 + r) * 1024 + k0 + gs * 8;
      size_t bo_ = (size_t)r * 1024 + k0 + gs * 8;
      gld16(xnh + ao, &Ah[(w * 32 + i2 * 16) * 32]);
      gld16(xnl + ao, &Al[(w * 32 + i2 * 16) * 32]);
      gld16(bsh + bo_, &Bh[(w * 32 + i2 * 16) * 32]);
      gld16(bsl + bo_, &Bl[(w * 32 + i2 * 16) * 32]);
    }
    asm volatile("s_waitcnt vmcnt(0)" ::: "memory");
    __syncthreads();
    f16x8 ah[2], al[2];
    #pragma unroll
    for (int mr = 0; mr < 2; ++mr) {
      int arow = w * 32 + mr * 16 + (lane & 15);
      int ag = (lane >> 4) ^ ((arow >> 1) & 3);
      ah[mr] = *(f16x8*)&Ah[arow * 32 + ag * 8];
      al[mr] = *(f16x8*)&Al[arow * 32 + ag * 8];
    }
    #pragma unroll
    for (int nb = 0; nb < 8; ++nb) {
      int brow = nb * 16 + (lane & 15);
      int bg = (lane >> 4) ^ ((brow >> 1) & 3);
      f16x8 b8h = *(f16x8*)&Bh[brow * 32 + bg * 8];
      f16x8 b8l = *(f16x8*)&Bl[brow * 32 + bg * 8];
      #pragma unroll
      for (int mr = 0; mr < 2; ++mr) {
        om[mr][nb] = __builtin_amdgcn_mfma_f32_16x16x32_f16(ah[mr], b8h, om[mr][nb], 0, 0, 0);
        oc[mr][nb] = __builtin_amdgcn_mfma_f32_16x16x32_f16(ah[mr], b8l, oc[mr][nb], 0, 0, 0);
        oc[mr][nb] = __builtin_amdgcn_mfma_f32_16x16x32_f16(al[mr], b8h, oc[mr][nb], 0, 0, 0);
      }
    }
  }
  // epilogue: D col = lane&15 (n), row = (lane>>4)*4 + r2 (m)
  int bb = m0 >> 11, tb = m0 & 2047;
  if (which < 2) {
    _Float16* OH = (which == 0) ? qh : kh;
    _Float16* OL = (which == 0) ? ql : kl;
    size_t base = (size_t)(bb * 8 + h) * 2048 * 128;
    #pragma unroll
    for (int mr = 0; mr < 2; ++mr)
      #pragma unroll
      for (int r2 = 0; r2 < 4; ++r2) {
        int t = tb + w * 32 + mr * 16 + ((lane >> 4) << 2) + r2;
        size_t roff = base + (size_t)t * 128 + (lane & 15);
        #pragma unroll
        for (int nb = 0; nb < 8; ++nb) {
          float v = om[mr][nb][r2] + oc[mr][nb][r2] * (1.0f / 2048.0f);
          _Float16 hh, ll;
          split_f16(v, hh, ll);
          OH[roff + nb * 16] = hh;
          OL[roff + nb * 16] = ll;
        }
      }
  } else {
    size_t base = (size_t)(bb * 8 + h) * 128 * 2048;
    #pragma unroll
    for (int mr = 0; mr < 2; ++mr) {
      int t4 = tb + w * 32 + mr * 16 + ((lane >> 4) << 2);
      #pragma unroll
      for (int nb = 0; nb < 8; ++nb) {
        int col = nb * 16 + (lane & 15);
        size_t off = base + (size_t)col * 2048 + t4;
        f16x4 hv, lv;
        #pragma unroll
        for (int r2 = 0; r2 < 4; ++r2) {
          _Float16 hh, ll;
          split_f16(om[mr][nb][r2] + oc[mr][nb][r2] * (1.0f / 2048.0f), hh, ll);
          hv[r2] = hh; lv[r2] = ll;
        }
        *(f16x4*)(vth + off) = hv;
        *(f16x4*)(vtl + off) = lv;
      }
    }
  }
}

// ---------------- kernel 4: x += attn @ Wo + bo, double-f16 MFMA ----------------
__global__ __launch_bounds__(256) void k_proj_res(
    const _Float16* __restrict__ ah_, const _Float16* __restrict__ al_,
    const _Float16* __restrict__ wth, const _Float16* __restrict__ wtl,
    const float* __restrict__ bo, float* __restrict__ x_io) {
  __shared__ __align__(16) _Float16 Ah[128 * 64], Al[128 * 64];
  __shared__ __align__(16) _Float16 Bh[128 * 64], Bl[128 * 64];
  int n0 = blockIdx.x * 128;
  int m0 = blockIdx.y * 128;
  int tid = threadIdx.x, w = tid >> 6, lane = tid & 63;
  f32x4 om[2][8], oc[2][8];
  const f32x4 zero4 = {0.f, 0.f, 0.f, 0.f};
  #pragma unroll
  for (int mr = 0; mr < 2; ++mr)
    #pragma unroll
    for (int nb = 0; nb < 8; ++nb) { om[mr][nb] = zero4; oc[mr][nb] = zero4; }

  for (int k0 = 0; k0 < 1024; k0 += 64) {
    __syncthreads();
    #pragma unroll
    for (int i2 = 0; i2 < 4; ++i2) {
      int r = w * 32 + i2 * 8 + (lane >> 3);
      int gs = (lane & 7) ^ (r & 7);
      size_t ao = (size_t)(m0 + r) * 1024 + k0 + gs * 8;
      size_t bo_ = (size_t)(n0 + r) * 1024 + k0 + gs * 8;
      gld16(ah_ + ao, &Ah[(w * 32 + i2 * 8) * 64]);
      gld16(al_ + ao, &Al[(w * 32 + i2 * 8) * 64]);
      gld16(wth + bo_, &Bh[(w * 32 + i2 * 8) * 64]);
      gld16(wtl + bo_, &Bl[(w * 32 + i2 * 8) * 64]);
    }
    asm volatile("s_waitcnt vmcnt(0)" ::: "memory");
    __syncthreads();
    #pragma unroll
    for (int k2 = 0; k2 < 2; ++k2) {
      f16x8 ah[2], al[2];
      #pragma unroll
      for (int mr = 0; mr < 2; ++mr) {
        int arow = w * 32 + mr * 16 + (lane & 15);
        int ag = (k2 * 4 + (lane >> 4)) ^ (arow & 7);
        ah[mr] = *(f16x8*)&Ah[arow * 64 + ag * 8];
        al[mr] = *(f16x8*)&Al[arow * 64 + ag * 8];
      }
      #pragma unroll
      for (int nb = 0; nb < 8; ++nb) {
        int brow = nb * 16 + (lane & 15);
        int bg = (k2 * 4 + (lane >> 4)) ^ (brow & 7);
        f16x8 b8h = *(f16x8*)&Bh[brow * 64 + bg * 8];
        f16x8 b8l = *(f16x8*)&Bl[brow * 64 + bg * 8];
        #pragma unroll
        for (int mr = 0; mr < 2; ++mr) {
          om[mr][nb] = __builtin_amdgcn_mfma_f32_16x16x32_f16(ah[mr], b8h, om[mr][nb], 0, 0, 0);
          oc[mr][nb] = __builtin_amdgcn_mfma_f32_16x16x32_f16(ah[mr], b8l, oc[mr][nb], 0, 0, 0);
          oc[mr][nb] = __builtin_amdgcn_mfma_f32_16x16x32_f16(al[mr], b8h, oc[mr][nb], 0, 0, 0);
        }
      }
    }
  }
  #pragma unroll
  for (int mr = 0; mr < 2; ++mr)
    #pragma unroll
    for (int nb = 0; nb < 8; ++nb) {
      int col = n0 + nb * 16 + (lane & 15);
      float bov = bo[col];
      #pragma unroll
      for (int r2 = 0; r2 < 4; ++r2) {
        int gm = m0 + w * 32 + mr * 16 + ((lane >> 4) << 2) + r2;
        float* p = x_io + (size_t)gm * 1024 + col;
        *p += om[mr][nb][r2] + oc[mr][nb][r2] * (1.0f / 2048.0f) + bov;
      }
    }
}

// ---------------- kernel 3: causal flash attention, double-f16 MFMA ----------------
// Paired Q-tiles: block handles qt = qs and qt = 31-qs (uniform 66 tile-units/block,
// zero tail). Double-buffered K/V staging: stage(t+1) issued BEFORE compute(t),
// one vmcnt(0)+barrier per tile. LDS 72KB -> 2 blocks/CU steady (8 waves/CU).
__global__ __launch_bounds__(256) void k_attn(
    const _Float16* __restrict__ qhp, const _Float16* __restrict__ qlp,
    const _Float16* __restrict__ khp, const _Float16* __restrict__ klp,
    const _Float16* __restrict__ vthp, const _Float16* __restrict__ vtlp,
    _Float16* __restrict__ attn_h, _Float16* __restrict__ attn_l) {
  __shared__ __align__(16) _Float16 Ksh[2][32 * 128];  // 16 KB
  __shared__ __align__(16) _Float16 Ksl[2][32 * 128];  // 16 KB
  __shared__ __align__(16) _Float16 Vh[2][128 * 32];   // 16 KB
  __shared__ __align__(16) _Float16 Vl[2][128 * 32];   // 16 KB
  __shared__ __align__(16) _Float16 Ph4[4][16 * 32];   // 4 KB
  __shared__ __align__(16) _Float16 Pl4[4][16 * 32];   // 4 KB

  int h = blockIdx.y, b = blockIdx.z;
  int qs = blockIdx.x;  // 0..15; pair (qs, 31-qs)
  int tid = threadIdx.x;
  int w = tid >> 6, lane = tid & 63;

  size_t bh = (size_t)(b * 8 + h) * 2048 * 128;
  const _Float16* qhb = qhp + bh;
  const _Float16* qlb = qlp + bh;
  const _Float16* khb = khp + bh;
  const _Float16* klb = klp + bh;
  const _Float16* vhb = vthp + bh;   // [d][t]
  const _Float16* vlb = vtlp + bh;
  _Float16* Ph = &Ph4[w][0];
  _Float16* Pl = &Pl4[w][0];

  const f32x4 zero4 = {0.f, 0.f, 0.f, 0.f};

  auto stage = [&](int cur, int j0) {
    #pragma unroll
    for (int i2 = 0; i2 < 2; ++i2) {
      int r = w * 8 + i2 * 4 + (lane >> 4);
      int gs = (lane & 15) ^ (r & 7);
      size_t go = (size_t)(j0 + r) * 128 + gs * 8;
      gld16(khb + go, &Ksh[cur][(w * 8 + i2 * 4) * 128]);
      gld16(klb + go, &Ksl[cur][(w * 8 + i2 * 4) * 128]);
    }
    #pragma unroll
    for (int i2 = 0; i2 < 2; ++i2) {
      int r = w * 32 + i2 * 16 + (lane >> 2);
      int gs = (lane & 3) ^ ((r >> 1) & 3);
      size_t go = (size_t)r * 2048 + j0 + gs * 8;
      gld16(vhb + go, &Vh[cur][(w * 32 + i2 * 16) * 32]);
      gld16(vlb + go, &Vl[cur][(w * 32 + i2 * 16) * 32]);
    }
  };

  #pragma unroll 1
  for (int pi = 0; pi < 2; ++pi) {
    int qt = pi ? (31 - qs) : qs;
    int t0 = qt << 6;
    int tW = t0 + w * 16;
    int rowBase = tW + ((lane >> 4) << 2);

    // Q fragments: lane l -> row l&15, d = kk*32 + (l>>4)*8 ..
    size_t qoff = (size_t)(tW + (lane & 15)) * 128 + ((lane >> 4) << 3);
    f16x8 qfh[4], qfl[4];
    #pragma unroll
    for (int kk = 0; kk < 4; ++kk) {
      qfh[kk] = *(const f16x8*)(qhb + qoff + kk * 32);
      qfl[kk] = *(const f16x8*)(qlb + qoff + kk * 32);
    }

    f32x4 om[8], oc[8];
    #pragma unroll
    for (int db = 0; db < 8; ++db) { om[db] = zero4; oc[db] = zero4; }
    float mreg[4], lreg[4];
    #pragma unroll
    for (int r2 = 0; r2 < 4; ++r2) { mreg[r2] = -INFINITY; lreg[r2] = 0.f; }

    int nt = 2 * qt + 2;   // KV tiles of 32
    stage(0, 0);
    asm volatile("s_waitcnt vmcnt(0)" ::: "memory");
    __syncthreads();
    int cur = 0;

    #pragma unroll 1
    for (int t = 0; t < nt; ++t) {
      if (t + 1 < nt) stage(cur ^ 1, (t + 1) * 32);  // prefetch in flight
      int j0 = t * 32;

      // ---- QK^T: S[16 q][32 kv]; main + corr accumulators ----
      f32x4 sm[2], sc[2];
      #pragma unroll
      for (int nb = 0; nb < 2; ++nb) { sm[nb] = zero4; sc[nb] = zero4; }
      #pragma unroll
      for (int kk = 0; kk < 4; ++kk) {
        #pragma unroll
        for (int nb = 0; nb < 2; ++nb) {
          int krow = nb * 16 + (lane & 15);
          int kg = (kk * 4 + (lane >> 4)) ^ (krow & 7);
          f16x8 kfh = *(f16x8*)&Ksh[cur][krow * 128 + kg * 8];
          f16x8 kfl = *(f16x8*)&Ksl[cur][krow * 128 + kg * 8];
          sm[nb] = __builtin_amdgcn_mfma_f32_16x16x32_f16(qfh[kk], kfh, sm[nb], 0, 0, 0);
          sc[nb] = __builtin_amdgcn_mfma_f32_16x16x32_f16(qfh[kk], kfl, sc[nb], 0, 0, 0);
          sc[nb] = __builtin_amdgcn_mfma_f32_16x16x32_f16(qfl[kk], kfh, sc[nb], 0, 0, 0);
        }
      }

      // ---- scale + causal mask + online softmax ----
      float rmax[4];
      #pragma unroll
      for (int r2 = 0; r2 < 4; ++r2) rmax[r2] = -INFINITY;
      #pragma unroll
      for (int nb = 0; nb < 2; ++nb) {
        int col = j0 + nb * 16 + (lane & 15);
        #pragma unroll
        for (int r2 = 0; r2 < 4; ++r2) {
          float sv = (sm[nb][r2] + sc[nb][r2] * (1.0f / 2048.0f)) * 0.03125f;
          sv = (col > rowBase + r2) ? -INFINITY : sv;
          sm[nb][r2] = sv;
          rmax[r2] = fmaxf(rmax[r2], sv);
        }
      }
      #pragma unroll
      for (int mk = 1; mk < 16; mk <<= 1)
        #pragma unroll
        for (int r2 = 0; r2 < 4; ++r2)
          rmax[r2] = fmaxf(rmax[r2], __shfl_xor(rmax[r2], mk, 64));
      float alpha[4], rsum[4];
      bool newmax = false;
      #pragma unroll
      for (int r2 = 0; r2 < 4; ++r2) {
        float mnew = fmaxf(mreg[r2], rmax[r2]);
        newmax |= (mnew > mreg[r2]);
        alpha[r2] = __expf(mreg[r2] - mnew);
        mreg[r2] = mnew;
        rsum[r2] = 0.f;
      }
      #pragma unroll
      for (int nb = 0; nb < 2; ++nb)
        #pragma unroll
        for (int r2 = 0; r2 < 4; ++r2) {
          float p = __expf(sm[nb][r2] - mreg[r2]);
          sm[nb][r2] = p;
          rsum[r2] += p;
        }
      #pragma unroll
      for (int mk = 1; mk < 16; mk <<= 1)
        #pragma unroll
        for (int r2 = 0; r2 < 4; ++r2)
          rsum[r2] += __shfl_xor(rsum[r2], mk, 64);
      #pragma unroll
      for (int r2 = 0; r2 < 4; ++r2)
        lreg[r2] = lreg[r2] * alpha[r2] + rsum[r2];

      // ---- P*2^14 -> hi/lo planes in per-wave LDS (granule-XOR swizzle) ----
      #pragma unroll
      for (int nb = 0; nb < 2; ++nb) {
        int col = nb * 16 + (lane & 15);
        #pragma unroll
        for (int r2 = 0; r2 < 4; ++r2) {
          int prow = ((lane >> 4) << 2) + r2;
          int sg = (col >> 3) ^ ((prow >> 1) & 3);
          float ps = sm[nb][r2] * 16384.0f;
          _Float16 hh, ll;
          split_f16(ps, hh, ll);
          Ph[prow * 32 + sg * 8 + (col & 7)] = hh;
          Pl[prow * 32 + sg * 8 + (col & 7)] = ll;
        }
      }

      // ---- rescale O (skipped when no lane saw a new row-max: alpha == 1) ----
      if (__any((int)newmax)) {
        #pragma unroll
        for (int db = 0; db < 8; ++db)
          #pragma unroll
          for (int r2 = 0; r2 < 4; ++r2) {
            om[db][r2] *= alpha[r2];
            oc[db][r2] *= alpha[r2];
          }
      }

      // ---- PV: O[16 q][128 d] += P[16][32] * V[32][128] ----
      {
        int prow = lane & 15;
        int pg = (lane >> 4) ^ ((prow >> 1) & 3);
        f16x8 pah = *(f16x8*)&Ph[prow * 32 + pg * 8];
        f16x8 pal = *(f16x8*)&Pl[prow * 32 + pg * 8];
        #pragma unroll
        for (int db = 0; db < 8; ++db) {
          int vrow = db * 16 + (lane & 15);
          int vg = (lane >> 4) ^ ((vrow >> 1) & 3);
          f16x8 vfh = *(f16x8*)&Vh[cur][vrow * 32 + vg * 8];
          f16x8 vfl = *(f16x8*)&Vl[cur][vrow * 32 + vg * 8];
          om[db] = __builtin_amdgcn_mfma_f32_16x16x32_f16(pah, vfh, om[db], 0, 0, 0);
          oc[db] = __builtin_amdgcn_mfma_f32_16x16x32_f16(pah, vfl, oc[db], 0, 0, 0);
          oc[db] = __builtin_amdgcn_mfma_f32_16x16x32_f16(pal, vfh, oc[db], 0, 0, 0);
        }
      }

      asm volatile("s_waitcnt vmcnt(0)" ::: "memory");  // next tile's loads done
      __syncthreads();                                   // all waves done with cur
      cur ^= 1;
    }

    // epilogue: v = (main + corr/2048) / (2^14 * l), written as hi/lo f16 planes
    // (register-only + global stores: no LDS reads -> no barrier needed before
    //  the next pair's prologue staging)
    size_t obase = ((size_t)(b * 2048 + rowBase)) * 1024 + h * 128 + (lane & 15);
    #pragma unroll
    for (int r2 = 0; r2 < 4; ++r2) {
      float inv = 1.f / (lreg[r2] * 16384.0f);
      #pragma unroll
      for (int db = 0; db < 8; ++db) {
        float v = (om[db][r2] + oc[db][r2] * (1.0f / 2048.0f)) * inv;
        _Float16 hh, ll;
        split_f16(v, hh, ll);
        attn_h[obase + (size_t)r2 * 1024 + db * 16] = hh;
        attn_l[obase + (size_t)r2 * 1024 + db * 16] = ll;
      }
    }
  }
}

// ---------------- kernel 6: noisy top-k router ----------------
__global__ __launch_bounds__(256) void k_router(
    const float* __restrict__ xn, const float* __restrict__ Wr,
    const float* __restrict__ br, const float* __restrict__ Wn,
    const float* __restrict__ bn, float* __restrict__ rp_out,
    float* __restrict__ idx_out) {
  int wave = threadIdx.x >> 6, lane = threadIdx.x & 63;
  int r = blockIdx.x * 4 + wave;
  const float* xr = xn + (size_t)r * 1024;
  float acc[16];
  #pragma unroll
  for (int i = 0; i < 16; ++i) acc[i] = 0.f;
  int cbase = lane * 16;
  for (int cc = 0; cc < 16; ++cc) {
    int c = cbase + cc;
    float xv = xr[c];
    const float4* wr4 = (const float4*)(Wr + (size_t)c * 8);
    float4 w0 = wr4[0], w1 = wr4[1];
    acc[0] += xv * w0.x; acc[1] += xv * w0.y; acc[2] += xv * w0.z; acc[3] += xv * w0.w;
    acc[4] += xv * w1.x; acc[5] += xv * w1.y; acc[6] += xv * w1.z; acc[7] += xv * w1.w;
    const float4* wn4 = (const float4*)(Wn + (size_t)c * 8);
    float4 n0 = wn4[0], n1 = wn4[1];
    acc[8]  += xv * n0.x; acc[9]  += xv * n0.y; acc[10] += xv * n0.z; acc[11] += xv * n0.w;
    acc[12] += xv * n1.x; acc[13] += xv * n1.y; acc[14] += xv * n1.z; acc[15] += xv * n1.w;
  }
  #pragma unroll
  for (int i = 0; i < 16; ++i) {
    #pragma unroll
    for (int off = 32; off > 0; off >>= 1) acc[i] += __shfl_down(acc[i], off, 64);
  }
  if (lane == 0) {
    float noisy[8];
    uint32_t nbase = (uint32_t)r * 8u;
    #pragma unroll
    for (int e = 0; e < 8; ++e) {
      float lg = acc[e] + br[e];
      float x = acc[8 + e] + bn[e];
      float sp = __fadd_rn(fmaxf(x, 0.f), log1pf(expf(-fabsf(x))));
      float nz = jax_noise(nbase + (uint32_t)e);
      noisy[e] = __fadd_rn(lg, __fmul_rn(nz, sp));
    }
    float v1 = -INFINITY, v2 = -INFINITY;
    int i1 = 0, i2 = 0;
    #pragma unroll
    for (int e = 0; e < 8; ++e) {
      float vv = noisy[e];
      if (vv > v1) { v2 = v1; i2 = i1; v1 = vv; i1 = e; }
      else if (vv > v2) { v2 = vv; i2 = e; }
    }
    float e2 = expf(v2 - v1);
    float ssum = 1.f + e2;
    float p1 = 1.f / ssum, p2 = e2 / ssum;
    float rp[8];
    #pragma unroll
    for (int e = 0; e < 8; ++e) rp[e] = 0.f;
    rp[i1] = p1; rp[i2] = p2;
    float* op = rp_out + (size_t)r * 8;
    #pragma unroll
    for (int e = 0; e < 8; ++e) op[e] = rp[e];
    idx_out[(size_t)r * 2]     = (float)i1;
    idx_out[(size_t)r * 2 + 1] = (float)i2;
  }
}

// ---------------- launch ----------------
extern "C" void kernel_launch(void* const* d_in, const int* in_sizes, int n_in,
                              void* d_out, int out_size, void* d_ws, size_t ws_size,
                              hipStream_t stream) {
  const int*   idx = (const int*)d_in[0];
  const float* tok = (const float*)d_in[1];
  const float* pos = (const float*)d_in[2];
  const float* Wq  = (const float*)d_in[3];
  const float* Wk  = (const float*)d_in[4];
  const float* Wv  = (const float*)d_in[5];
  const float* Wo  = (const float*)d_in[6];
  const float* bo  = (const float*)d_in[7];
  const float* g1  = (const float*)d_in[8];
  const float* b1  = (const float*)d_in[9];
  const float* g2  = (const float*)d_in[10];
  const float* b2  = (const float*)d_in[11];
  const float* Wr  = (const float*)d_in[12];
  const float* br  = (const float*)d_in[13];
  const float* Wn  = (const float*)d_in[14];
  const float* bn  = (const float*)d_in[15];

  float* out_xnorm = (float*)d_out;             // 4*2048*1024
  float* out_rp    = out_xnorm + 8388608;       // 4*2048*8
  float* out_idx   = out_rp + 65536;            // 4*2048*2 (written as float)
  float* out_x     = out_idx + 16384;           // 4*2048*1024

  // workspace: 8 f16 planes x 16 MB = 128 MB
  _Float16* xnh  = (_Float16*)d_ws;
  _Float16* xnl  = xnh + 8388608;
  _Float16* qhp  = xnl + 8388608;
  _Float16* qlp  = qhp + 8388608;
  _Float16* khp  = qlp + 8388608;
  _Float16* klp  = khp + 8388608;
  _Float16* vthp = klp + 8388608;               // [bh][d][t]
  _Float16* vtlp = vthp + 8388608;
  // attn planes reuse xn planes (xn fully consumed by k_qkv)
  _Float16* attn_h = xnh;
  _Float16* attn_l = xnl;
  // weight hi/lo planes stashed in out_xnorm (16 MB of 32 MB);
  // fully overwritten later by k_ln2 after k_proj_res has consumed them.
  _Float16* wqt_h = (_Float16*)out_xnorm;       // 24*128*1024
  _Float16* wqt_l = wqt_h + 3145728;
  _Float16* wot_h = wqt_l + 3145728;            // 1024*1024
  _Float16* wot_l = wot_h + 1048576;

  k_wsplit<<<32, 128, 0, stream>>>(Wq, Wk, Wv, Wo, wqt_h, wqt_l, wot_h, wot_l);
  k_embed_ln1<<<8192, 256, 0, stream>>>(idx, tok, pos, g1, b1, out_x, xnh, xnl);
  k_qkv<<<dim3(24, 64), 256, 0, stream>>>(xnh, xnl, wqt_h, wqt_l,
                                          qhp, qlp, khp, klp, vthp, vtlp);
  k_attn<<<dim3(16, 8, 4), 256, 0, stream>>>(qhp, qlp, khp, klp, vthp, vtlp,
                                             attn_h, attn_l);
  k_proj_res<<<dim3(8, 64), 256, 0, stream>>>(attn_h, attn_l, wot_h, wot_l, bo, out_x);
  k_ln2<<<8192, 256, 0, stream>>>(out_x, g2, b2, out_xnorm);
  k_router<<<2048, 256, 0, stream>>>(out_xnorm, Wr, br, Wn, bn, out_rp, out_idx);
}

// Round 8
// 967.538 us; speedup vs baseline: 1.1214x; 1.1214x over previous
//
#include <hip/hip_runtime.h>
#include <math.h>
#include <stdint.h>

typedef __attribute__((ext_vector_type(8))) _Float16 f16x8;  // 8 f16 = 4 VGPR
typedef __attribute__((ext_vector_type(4))) _Float16 f16x4;  // 8 bytes
typedef __attribute__((ext_vector_type(4))) float f32x4;

// Dekker-style split: x ~= hi + lo/2048, both f16, lo kept out of denormal range.
__device__ __forceinline__ void split_f16(float x, _Float16& h, _Float16& l) {
  h = (_Float16)x;
  l = (_Float16)((x - (float)h) * 2048.0f);
}

__device__ __forceinline__ void gld16(const void* g, void* l) {
  __builtin_amdgcn_global_load_lds(
      (const __attribute__((address_space(1))) void*)g,
      (__attribute__((address_space(3))) void*)l, 16, 0, 0);
}

// ---------------- JAX threefry2x32 (key = [0,42]) + normal transform ----------------
__device__ __forceinline__ void threefry2x32_42(uint32_t x0, uint32_t x1,
                                                uint32_t& o0, uint32_t& o1) {
  const uint32_t k0 = 0u, k1 = 42u;
  const uint32_t k2 = k0 ^ k1 ^ 0x1BD11BDAu;
  x0 += k0; x1 += k1;
#define TF_R(r) { x0 += x1; x1 = (x1 << (r)) | (x1 >> (32 - (r))); x1 ^= x0; }
  TF_R(13) TF_R(15) TF_R(26) TF_R(6)
  x0 += k1; x1 += k2 + 1u;
  TF_R(17) TF_R(29) TF_R(16) TF_R(24)
  x0 += k2; x1 += k0 + 2u;
  TF_R(13) TF_R(15) TF_R(26) TF_R(6)
  x0 += k0; x1 += k1 + 3u;
  TF_R(17) TF_R(29) TF_R(16) TF_R(24)
  x0 += k1; x1 += k2 + 4u;
  TF_R(13) TF_R(15) TF_R(26) TF_R(6)
  x0 += k2; x1 += k0 + 5u;
#undef TF_R
  o0 = x0; o1 = x1;
}

__device__ __forceinline__ float jax_erfinv_f32(float x) {
  float xx = __fmul_rn(x, x);
  float w = -log1pf(-xx);
  float p;
  if (w < 5.0f) {
    w = __fadd_rn(w, -2.5f);
    p = 2.81022636e-08f;
    p = __fadd_rn(3.43273939e-07f, __fmul_rn(p, w));
    p = __fadd_rn(-3.5233877e-06f, __fmul_rn(p, w));
    p = __fadd_rn(-4.39150654e-06f, __fmul_rn(p, w));
    p = __fadd_rn(0.00021858087f, __fmul_rn(p, w));
    p = __fadd_rn(-0.00125372503f, __fmul_rn(p, w));
    p = __fadd_rn(-0.00417768164f, __fmul_rn(p, w));
    p = __fadd_rn(0.246640727f, __fmul_rn(p, w));
    p = __fadd_rn(1.50140941f, __fmul_rn(p, w));
  } else {
    w = __fadd_rn(sqrtf(w), -3.0f);
    p = -0.000200214257f;
    p = __fadd_rn(0.000100950558f, __fmul_rn(p, w));
    p = __fadd_rn(0.00134934322f, __fmul_rn(p, w));
    p = __fadd_rn(-0.00367342844f, __fmul_rn(p, w));
    p = __fadd_rn(0.00573950773f, __fmul_rn(p, w));
    p = __fadd_rn(-0.0076224613f, __fmul_rn(p, w));
    p = __fadd_rn(0.00943887047f, __fmul_rn(p, w));
    p = __fadd_rn(1.00167406f, __fmul_rn(p, w));
    p = __fadd_rn(2.83297682f, __fmul_rn(p, w));
  }
  return __fmul_rn(p, x);
}

__device__ __forceinline__ float jax_noise(uint32_t n) {
  uint32_t o0, o1;
  threefry2x32_42(0u, n, o0, o1);
  uint32_t bits = o0 ^ o1;
  uint32_t fb = (bits >> 9) | 0x3F800000u;
  float f = __fadd_rn(__uint_as_float(fb), -1.0f);
  const float lo = __uint_as_float(0xBF7FFFFFu);
  float u = __fadd_rn(__fmul_rn(f, 2.0f), lo);
  u = fmaxf(lo, u);
  return __fmul_rn(__uint_as_float(0x3FB504F3u), jax_erfinv_f32(u));
}

// ---------------- block reduction helper (256 threads = 4 waves) ----------------
__device__ __forceinline__ float block_sum_256(float v, float* buf) {
  #pragma unroll
  for (int off = 32; off > 0; off >>= 1) v += __shfl_down(v, off, 64);
  int lane = threadIdx.x & 63;
  int w = threadIdx.x >> 6;
  if (lane == 0) buf[w] = v;
  __syncthreads();
  return buf[0] + buf[1] + buf[2] + buf[3];
}

// ---------------- kernel 0: weight transpose + split ----------------
__global__ __launch_bounds__(128) void k_wsplit(
    const float* __restrict__ Wq, const float* __restrict__ Wk,
    const float* __restrict__ Wv, const float* __restrict__ Wo,
    _Float16* __restrict__ wqt_h, _Float16* __restrict__ wqt_l,
    _Float16* __restrict__ wot_h, _Float16* __restrict__ wot_l) {
  int z = blockIdx.x, tid = threadIdx.x;
  const float* src;
  int ldn, n;
  _Float16 *dh, *dl;
  if (z < 24) {
    int which = z >> 3, h = z & 7;
    src = ((which == 0) ? Wq : (which == 1) ? Wk : Wv) + (size_t)h * 1024 * 128;
    ldn = 128; n = tid;
    dh = wqt_h + (size_t)z * 128 * 1024 + (size_t)n * 1024;
    dl = wqt_l + (size_t)z * 128 * 1024 + (size_t)n * 1024;
  } else {
    int zz = z - 24;
    src = Wo; ldn = 1024; n = zz * 128 + tid;
    dh = wot_h + (size_t)n * 1024;
    dl = wot_l + (size_t)n * 1024;
  }
  for (int k0 = 0; k0 < 1024; k0 += 16) {
    f16x8 hv0, hv1, lv0, lv1;
    #pragma unroll
    for (int j = 0; j < 8; ++j) {
      _Float16 hh, ll;
      split_f16(src[(size_t)(k0 + j) * ldn + n], hh, ll);
      hv0[j] = hh; lv0[j] = ll;
    }
    #pragma unroll
    for (int j = 0; j < 8; ++j) {
      _Float16 hh, ll;
      split_f16(src[(size_t)(k0 + 8 + j) * ldn + n], hh, ll);
      hv1[j] = hh; lv1[j] = ll;
    }
    *(f16x8*)(dh + k0) = hv0; *(f16x8*)(dh + k0 + 8) = hv1;
    *(f16x8*)(dl + k0) = lv0; *(f16x8*)(dl + k0 + 8) = lv1;
  }
}

// ---------------- kernel 1: embed + LN1 (xn written as hi/lo f16 planes) ----------------
__global__ __launch_bounds__(256) void k_embed_ln1(
    const int* __restrict__ idx, const float* __restrict__ tok,
    const float* __restrict__ pos, const float* __restrict__ g1,
    const float* __restrict__ b1, float* __restrict__ x_out,
    _Float16* __restrict__ xnh, _Float16* __restrict__ xnl) {
  __shared__ float bufA[4], bufB[4];
  int r = blockIdx.x;
  int t = r & 2047;
  int token = idx[r];
  int c4 = threadIdx.x;
  float4 tv = *((const float4*)(tok + (size_t)token * 1024) + c4);
  float4 pv = *((const float4*)(pos + (size_t)t * 1024) + c4);
  float4 xv = make_float4(tv.x + pv.x, tv.y + pv.y, tv.z + pv.z, tv.w + pv.w);
  *((float4*)(x_out + (size_t)r * 1024) + c4) = xv;
  float mu = block_sum_256(xv.x + xv.y + xv.z + xv.w, bufA) * (1.0f / 1024.0f);
  float d0 = xv.x - mu, d1 = xv.y - mu, d2 = xv.z - mu, d3 = xv.w - mu;
  float var = block_sum_256(d0*d0 + d1*d1 + d2*d2 + d3*d3, bufB) * (1.0f / 1024.0f);
  float rs = rsqrtf(var + 1e-5f);
  float4 gv = *((const float4*)g1 + c4);
  float4 bv = *((const float4*)b1 + c4);
  float xn0 = d0*rs*gv.x + bv.x, xn1 = d1*rs*gv.y + bv.y;
  float xn2 = d2*rs*gv.z + bv.z, xn3 = d3*rs*gv.w + bv.w;
  f16x4 hv, lv;
  _Float16 hh, ll;
  split_f16(xn0, hh, ll); hv[0] = hh; lv[0] = ll;
  split_f16(xn1, hh, ll); hv[1] = hh; lv[1] = ll;
  split_f16(xn2, hh, ll); hv[2] = hh; lv[2] = ll;
  split_f16(xn3, hh, ll); hv[3] = hh; lv[3] = ll;
  *(f16x4*)(xnh + (size_t)r * 1024 + c4 * 4) = hv;
  *(f16x4*)(xnl + (size_t)r * 1024 + c4 * 4) = lv;
}

// ---------------- kernel 5: LN2 ----------------
__global__ __launch_bounds__(256) void k_ln2(
    const float* __restrict__ x, const float* __restrict__ g2,
    const float* __restrict__ b2, float* __restrict__ xn_out) {
  __shared__ float bufA[4], bufB[4];
  int r = blockIdx.x;
  int c4 = threadIdx.x;
  float4 xv = *((const float4*)(x + (size_t)r * 1024) + c4);
  float mu = block_sum_256(xv.x + xv.y + xv.z + xv.w, bufA) * (1.0f / 1024.0f);
  float d0 = xv.x - mu, d1 = xv.y - mu, d2 = xv.z - mu, d3 = xv.w - mu;
  float var = block_sum_256(d0*d0 + d1*d1 + d2*d2 + d3*d3, bufB) * (1.0f / 1024.0f);
  float rs = rsqrtf(var + 1e-5f);
  float4 gv = *((const float4*)g2 + c4);
  float4 bv = *((const float4*)b2 + c4);
  float4 xn = make_float4(d0*rs*gv.x + bv.x, d1*rs*gv.y + bv.y,
                          d2*rs*gv.z + bv.z, d3*rs*gv.w + bv.w);
  *((float4*)(xn_out + (size_t)r * 1024) + c4) = xn;
}

// ---------------- kernel 2: QKV projection, double-f16 MFMA GEMM ----------------
// KSTEP=32: LDS 32KB -> high residency. grid (24, 64). 4 waves, 32 rows each.
__global__ __launch_bounds__(256) void k_qkv(
    const _Float16* __restrict__ xnh, const _Float16* __restrict__ xnl,
    const _Float16* __restrict__ wth, const _Float16* __restrict__ wtl,
    _Float16* __restrict__ qh, _Float16* __restrict__ ql,
    _Float16* __restrict__ kh, _Float16* __restrict__ kl,
    _Float16* __restrict__ vth, _Float16* __restrict__ vtl) {
  __shared__ __align__(16) _Float16 Ah[128 * 32], Al[128 * 32];  // 16 KB
  __shared__ __align__(16) _Float16 Bh[128 * 32], Bl[128 * 32];  // 16 KB
  int z = blockIdx.x;
  int which = z >> 3, h = z & 7;
  int m0 = blockIdx.y * 128;
  int tid = threadIdx.x, w = tid >> 6, lane = tid & 63;
  const _Float16* bsh = wth + (size_t)z * 128 * 1024;
  const _Float16* bsl = wtl + (size_t)z * 128 * 1024;
  f32x4 om[2][8], oc[2][8];
  const f32x4 zero4 = {0.f, 0.f, 0.f, 0.f};
  #pragma unroll
  for (int mr = 0; mr < 2; ++mr)
    #pragma unroll
    for (int nb = 0; nb < 8; ++nb) { om[mr][nb] = zero4; oc[mr][nb] = zero4; }

  for (int k0 = 0; k0 < 1024; k0 += 32) {
    __syncthreads();
    // wave w stages rows w*32..w*32+31 of A and B tiles (16 rows / inst)
    #pragma unroll
    for (int i2 = 0; i2 < 2; ++i2) {
      int r = w * 32 + i2 * 16 + (lane >> 2);
      int gs = (lane & 3) ^ ((r >> 1) & 3);
      size_t ao = (size_t)(m0 + r) * 1024 + k0 + gs * 8;
      size_t bo_ = (size_t)r * 1024 + k0 + gs * 8;
      gld16(xnh + ao, &Ah[(w * 32 + i2 * 16) * 32]);
      gld16(xnl + ao, &Al[(w * 32 + i2 * 16) * 32]);
      gld16(bsh + bo_, &Bh[(w * 32 + i2 * 16) * 32]);
      gld16(bsl + bo_, &Bl[(w * 32 + i2 * 16) * 32]);
    }
    asm volatile("s_waitcnt vmcnt(0)" ::: "memory");
    __syncthreads();
    f16x8 ah[2], al[2];
    #pragma unroll
    for (int mr = 0; mr < 2; ++mr) {
      int arow = w * 32 + mr * 16 + (lane & 15);
      int ag = (lane >> 4) ^ ((arow >> 1) & 3);
      ah[mr] = *(f16x8*)&Ah[arow * 32 + ag * 8];
      al[mr] = *(f16x8*)&Al[arow * 32 + ag * 8];
    }
    #pragma unroll
    for (int nb = 0; nb < 8; ++nb) {
      int brow = nb * 16 + (lane & 15);
      int bg = (lane >> 4) ^ ((brow >> 1) & 3);
      f16x8 b8h = *(f16x8*)&Bh[brow * 32 + bg * 8];
      f16x8 b8l = *(f16x8*)&Bl[brow * 32 + bg * 8];
      #pragma unroll
      for (int mr = 0; mr < 2; ++mr) {
        om[mr][nb] = __builtin_amdgcn_mfma_f32_16x16x32_f16(ah[mr], b8h, om[mr][nb], 0, 0, 0);
        oc[mr][nb] = __builtin_amdgcn_mfma_f32_16x16x32_f16(ah[mr], b8l, oc[mr][nb], 0, 0, 0);
        oc[mr][nb] = __builtin_amdgcn_mfma_f32_16x16x32_f16(al[mr], b8h, oc[mr][nb], 0, 0, 0);
      }
    }
  }
  // epilogue: D col = lane&15 (n), row = (lane>>4)*4 + r2 (m)
  int bb = m0 >> 11, tb = m0 & 2047;
  if (which < 2) {
    _Float16* OH = (which == 0) ? qh : kh;
    _Float16* OL = (which == 0) ? ql : kl;
    size_t base = (size_t)(bb * 8 + h) * 2048 * 128;
    #pragma unroll
    for (int mr = 0; mr < 2; ++mr)
      #pragma unroll
      for (int r2 = 0; r2 < 4; ++r2) {
        int t = tb + w * 32 + mr * 16 + ((lane >> 4) << 2) + r2;
        size_t roff = base + (size_t)t * 128 + (lane & 15);
        #pragma unroll
        for (int nb = 0; nb < 8; ++nb) {
          float v = om[mr][nb][r2] + oc[mr][nb][r2] * (1.0f / 2048.0f);
          _Float16 hh, ll;
          split_f16(v, hh, ll);
          OH[roff + nb * 16] = hh;
          OL[roff + nb * 16] = ll;
        }
      }
  } else {
    size_t base = (size_t)(bb * 8 + h) * 128 * 2048;
    #pragma unroll
    for (int mr = 0; mr < 2; ++mr) {
      int t4 = tb + w * 32 + mr * 16 + ((lane >> 4) << 2);
      #pragma unroll
      for (int nb = 0; nb < 8; ++nb) {
        int col = nb * 16 + (lane & 15);
        size_t off = base + (size_t)col * 2048 + t4;
        f16x4 hv, lv;
        #pragma unroll
        for (int r2 = 0; r2 < 4; ++r2) {
          _Float16 hh, ll;
          split_f16(om[mr][nb][r2] + oc[mr][nb][r2] * (1.0f / 2048.0f), hh, ll);
          hv[r2] = hh; lv[r2] = ll;
        }
        *(f16x4*)(vth + off) = hv;
        *(f16x4*)(vtl + off) = lv;
      }
    }
  }
}

// ---------------- kernel 4: x += attn @ Wo + bo, double-f16 MFMA ----------------
__global__ __launch_bounds__(256) void k_proj_res(
    const _Float16* __restrict__ ah_, const _Float16* __restrict__ al_,
    const _Float16* __restrict__ wth, const _Float16* __restrict__ wtl,
    const float* __restrict__ bo, float* __restrict__ x_io) {
  __shared__ __align__(16) _Float16 Ah[128 * 64], Al[128 * 64];
  __shared__ __align__(16) _Float16 Bh[128 * 64], Bl[128 * 64];
  int n0 = blockIdx.x * 128;
  int m0 = blockIdx.y * 128;
  int tid = threadIdx.x, w = tid >> 6, lane = tid & 63;
  f32x4 om[2][8], oc[2][8];
  const f32x4 zero4 = {0.f, 0.f, 0.f, 0.f};
  #pragma unroll
  for (int mr = 0; mr < 2; ++mr)
    #pragma unroll
    for (int nb = 0; nb < 8; ++nb) { om[mr][nb] = zero4; oc[mr][nb] = zero4; }

  for (int k0 = 0; k0 < 1024; k0 += 64) {
    __syncthreads();
    #pragma unroll
    for (int i2 = 0; i2 < 4; ++i2) {
      int r = w * 32 + i2 * 8 + (lane >> 3);
      int gs = (lane & 7) ^ (r & 7);
      size_t ao = (size_t)(m0 + r) * 1024 + k0 + gs * 8;
      size_t bo_ = (size_t)(n0 + r) * 1024 + k0 + gs * 8;
      gld16(ah_ + ao, &Ah[(w * 32 + i2 * 8) * 64]);
      gld16(al_ + ao, &Al[(w * 32 + i2 * 8) * 64]);
      gld16(wth + bo_, &Bh[(w * 32 + i2 * 8) * 64]);
      gld16(wtl + bo_, &Bl[(w * 32 + i2 * 8) * 64]);
    }
    asm volatile("s_waitcnt vmcnt(0)" ::: "memory");
    __syncthreads();
    #pragma unroll
    for (int k2 = 0; k2 < 2; ++k2) {
      f16x8 ah[2], al[2];
      #pragma unroll
      for (int mr = 0; mr < 2; ++mr) {
        int arow = w * 32 + mr * 16 + (lane & 15);
        int ag = (k2 * 4 + (lane >> 4)) ^ (arow & 7);
        ah[mr] = *(f16x8*)&Ah[arow * 64 + ag * 8];
        al[mr] = *(f16x8*)&Al[arow * 64 + ag * 8];
      }
      #pragma unroll
      for (int nb = 0; nb < 8; ++nb) {
        int brow = nb * 16 + (lane & 15);
        int bg = (k2 * 4 + (lane >> 4)) ^ (brow & 7);
        f16x8 b8h = *(f16x8*)&Bh[brow * 64 + bg * 8];
        f16x8 b8l = *(f16x8*)&Bl[brow * 64 + bg * 8];
        #pragma unroll
        for (int mr = 0; mr < 2; ++mr) {
          om[mr][nb] = __builtin_amdgcn_mfma_f32_16x16x32_f16(ah[mr], b8h, om[mr][nb], 0, 0, 0);
          oc[mr][nb] = __builtin_amdgcn_mfma_f32_16x16x32_f16(ah[mr], b8l, oc[mr][nb], 0, 0, 0);
          oc[mr][nb] = __builtin_amdgcn_mfma_f32_16x16x32_f16(al[mr], b8h, oc[mr][nb], 0, 0, 0);
        }
      }
    }
  }
  #pragma unroll
  for (int mr = 0; mr < 2; ++mr)
    #pragma unroll
    for (int nb = 0; nb < 8; ++nb) {
      int col = n0 + nb * 16 + (lane & 15);
      float bov = bo[col];
      #pragma unroll
      for (int r2 = 0; r2 < 4; ++r2) {
        int gm = m0 + w * 32 + mr * 16 + ((lane >> 4) << 2) + r2;
        float* p = x_io + (size_t)gm * 1024 + col;
        *p += om[mr][nb][r2] + oc[mr][nb][r2] * (1.0f / 2048.0f) + bov;
      }
    }
}

// ---------------- kernel 3: causal flash attention, double-f16 MFMA ----------------
// 8-wave blocks (512 thr), Q-tile = 128 rows (wave w: rows 16w..16w+15).
// In-block pairing qt in {qs, 15-qs}: grid 256 = 1 block/CU, uniform 68 KV-tiles.
// KVBLK=32 double-buffered; LDS 80KB; 2 waves/SIMD (vs 1 in prior rounds).
// Grid (x = b*8+h, y = qs) so a head's 8 blocks share id%8 -> same XCD L2.
__global__ __launch_bounds__(512) void k_attn(
    const _Float16* __restrict__ qhp, const _Float16* __restrict__ qlp,
    const _Float16* __restrict__ khp, const _Float16* __restrict__ klp,
    const _Float16* __restrict__ vthp, const _Float16* __restrict__ vtlp,
    _Float16* __restrict__ attn_h, _Float16* __restrict__ attn_l) {
  __shared__ __align__(16) _Float16 Ksh[2][32 * 128];  // 16 KB
  __shared__ __align__(16) _Float16 Ksl[2][32 * 128];  // 16 KB
  __shared__ __align__(16) _Float16 Vh[2][128 * 32];   // 16 KB
  __shared__ __align__(16) _Float16 Vl[2][128 * 32];   // 16 KB
  __shared__ __align__(16) _Float16 Ph8[8][16 * 32];   // 8 KB
  __shared__ __align__(16) _Float16 Pl8[8][16 * 32];   // 8 KB

  int bh_ = blockIdx.x;            // b*8 + h
  int b = bh_ >> 3, h = bh_ & 7;
  int qs = blockIdx.y;             // 0..7; pair (qs, 15-qs)
  int tid = threadIdx.x;
  int w = tid >> 6, lane = tid & 63;

  size_t bh = (size_t)(b * 8 + h) * 2048 * 128;
  const _Float16* qhb = qhp + bh;
  const _Float16* qlb = qlp + bh;
  const _Float16* khb = khp + bh;
  const _Float16* klb = klp + bh;
  const _Float16* vhb = vthp + bh;   // [d][t]
  const _Float16* vlb = vtlp + bh;
  _Float16* Ph = &Ph8[w][0];
  _Float16* Pl = &Pl8[w][0];

  const f32x4 zero4 = {0.f, 0.f, 0.f, 0.f};

  // per wave per tile: 2 K gld16 (hi/lo, rows 4w..4w+3) + 2 V gld16 (rows 16w..16w+15)
  auto stage = [&](int cur, int j0) {
    int kr = (w << 2) + (lane >> 4);
    int kg = (lane & 15) ^ (kr & 7);
    size_t kgo = (size_t)(j0 + kr) * 128 + kg * 8;
    gld16(khb + kgo, &Ksh[cur][(w << 2) * 128]);
    gld16(klb + kgo, &Ksl[cur][(w << 2) * 128]);
    int vr = (w << 4) + (lane >> 2);
    int vg = (lane & 3) ^ ((vr >> 1) & 3);
    size_t vgo = (size_t)vr * 2048 + j0 + vg * 8;
    gld16(vhb + vgo, &Vh[cur][(w << 4) * 32]);
    gld16(vlb + vgo, &Vl[cur][(w << 4) * 32]);
  };

  #pragma unroll 1
  for (int pi = 0; pi < 2; ++pi) {
    int qt = pi ? (15 - qs) : qs;
    int t0 = qt << 7;                  // 128-row Q-tile
    int tW = t0 + w * 16;
    int rowBase = tW + ((lane >> 4) << 2);

    // Q fragments: lane l -> row l&15, d = kk*32 + (l>>4)*8 ..
    size_t qoff = (size_t)(tW + (lane & 15)) * 128 + ((lane >> 4) << 3);
    f16x8 qfh[4], qfl[4];
    #pragma unroll
    for (int kk = 0; kk < 4; ++kk) {
      qfh[kk] = *(const f16x8*)(qhb + qoff + kk * 32);
      qfl[kk] = *(const f16x8*)(qlb + qoff + kk * 32);
    }

    f32x4 om[8], oc[8];
    #pragma unroll
    for (int db = 0; db < 8; ++db) { om[db] = zero4; oc[db] = zero4; }
    float mreg[4], lreg[4];
    #pragma unroll
    for (int r2 = 0; r2 < 4; ++r2) { mreg[r2] = -INFINITY; lreg[r2] = 0.f; }

    int nt = 4 * qt + 4;   // KV tiles of 32 covering rows 0..t0+127
    stage(0, 0);
    asm volatile("s_waitcnt vmcnt(0)" ::: "memory");
    __syncthreads();
    int cur = 0;

    #pragma unroll 1
    for (int t = 0; t < nt; ++t) {
      if (t + 1 < nt) stage(cur ^ 1, (t + 1) * 32);  // prefetch in flight
      int j0 = t * 32;

      // ---- QK^T: S[16 q][32 kv]; main + corr accumulators ----
      f32x4 sm[2], sc[2];
      #pragma unroll
      for (int nb = 0; nb < 2; ++nb) { sm[nb] = zero4; sc[nb] = zero4; }
      #pragma unroll
      for (int kk = 0; kk < 4; ++kk) {
        #pragma unroll
        for (int nb = 0; nb < 2; ++nb) {
          int krow = nb * 16 + (lane & 15);
          int kg = (kk * 4 + (lane >> 4)) ^ (krow & 7);
          f16x8 kfh = *(f16x8*)&Ksh[cur][krow * 128 + kg * 8];
          f16x8 kfl = *(f16x8*)&Ksl[cur][krow * 128 + kg * 8];
          sm[nb] = __builtin_amdgcn_mfma_f32_16x16x32_f16(qfh[kk], kfh, sm[nb], 0, 0, 0);
          sc[nb] = __builtin_amdgcn_mfma_f32_16x16x32_f16(qfh[kk], kfl, sc[nb], 0, 0, 0);
          sc[nb] = __builtin_amdgcn_mfma_f32_16x16x32_f16(qfl[kk], kfh, sc[nb], 0, 0, 0);
        }
      }

      // ---- scale + causal mask + online softmax ----
      float rmax[4];
      #pragma unroll
      for (int r2 = 0; r2 < 4; ++r2) rmax[r2] = -INFINITY;
      #pragma unroll
      for (int nb = 0; nb < 2; ++nb) {
        int col = j0 + nb * 16 + (lane & 15);
        #pragma unroll
        for (int r2 = 0; r2 < 4; ++r2) {
          float sv = (sm[nb][r2] + sc[nb][r2] * (1.0f / 2048.0f)) * 0.03125f;
          sv = (col > rowBase + r2) ? -INFINITY : sv;
          sm[nb][r2] = sv;
          rmax[r2] = fmaxf(rmax[r2], sv);
        }
      }
      #pragma unroll
      for (int mk = 1; mk < 16; mk <<= 1)
        #pragma unroll
        for (int r2 = 0; r2 < 4; ++r2)
          rmax[r2] = fmaxf(rmax[r2], __shfl_xor(rmax[r2], mk, 64));
      float alpha[4], rsum[4];
      bool newmax = false;
      #pragma unroll
      for (int r2 = 0; r2 < 4; ++r2) {
        float mnew = fmaxf(mreg[r2], rmax[r2]);
        newmax |= (mnew > mreg[r2]);
        alpha[r2] = __expf(mreg[r2] - mnew);
        mreg[r2] = mnew;
        rsum[r2] = 0.f;
      }
      #pragma unroll
      for (int nb = 0; nb < 2; ++nb)
        #pragma unroll
        for (int r2 = 0; r2 < 4; ++r2) {
          float p = __expf(sm[nb][r2] - mreg[r2]);
          sm[nb][r2] = p;
          rsum[r2] += p;
        }
      #pragma unroll
      for (int mk = 1; mk < 16; mk <<= 1)
        #pragma unroll
        for (int r2 = 0; r2 < 4; ++r2)
          rsum[r2] += __shfl_xor(rsum[r2], mk, 64);
      #pragma unroll
      for (int r2 = 0; r2 < 4; ++r2)
        lreg[r2] = lreg[r2] * alpha[r2] + rsum[r2];

      // ---- P*2^14 -> hi/lo planes in per-wave LDS (granule-XOR swizzle) ----
      #pragma unroll
      for (int nb = 0; nb < 2; ++nb) {
        int col = nb * 16 + (lane & 15);
        #pragma unroll
        for (int r2 = 0; r2 < 4; ++r2) {
          int prow = ((lane >> 4) << 2) + r2;
          int sg = (col >> 3) ^ ((prow >> 1) & 3);
          float ps = sm[nb][r2] * 16384.0f;
          _Float16 hh, ll;
          split_f16(ps, hh, ll);
          Ph[prow * 32 + sg * 8 + (col & 7)] = hh;
          Pl[prow * 32 + sg * 8 + (col & 7)] = ll;
        }
      }

      // ---- rescale O (skipped when no lane saw a new row-max: alpha == 1) ----
      if (__any((int)newmax)) {
        #pragma unroll
        for (int db = 0; db < 8; ++db)
          #pragma unroll
          for (int r2 = 0; r2 < 4; ++r2) {
            om[db][r2] *= alpha[r2];
            oc[db][r2] *= alpha[r2];
          }
      }

      // ---- PV: O[16 q][128 d] += P[16][32] * V[32][128] ----
      {
        int prow = lane & 15;
        int pg = (lane >> 4) ^ ((prow >> 1) & 3);
        f16x8 pah = *(f16x8*)&Ph[prow * 32 + pg * 8];
        f16x8 pal = *(f16x8*)&Pl[prow * 32 + pg * 8];
        #pragma unroll
        for (int db = 0; db < 8; ++db) {
          int vrow = db * 16 + (lane & 15);
          int vg = (lane >> 4) ^ ((vrow >> 1) & 3);
          f16x8 vfh = *(f16x8*)&Vh[cur][vrow * 32 + vg * 8];
          f16x8 vfl = *(f16x8*)&Vl[cur][vrow * 32 + vg * 8];
          om[db] = __builtin_amdgcn_mfma_f32_16x16x32_f16(pah, vfh, om[db], 0, 0, 0);
          oc[db] = __builtin_amdgcn_mfma_f32_16x16x32_f16(pah, vfl, oc[db], 0, 0, 0);
          oc[db] = __builtin_amdgcn_mfma_f32_16x16x32_f16(pal, vfh, oc[db], 0, 0, 0);
        }
      }

      asm volatile("s_waitcnt vmcnt(0)" ::: "memory");  // next tile's loads done
      __syncthreads();                                   // all waves done with cur
      cur ^= 1;
    }

    // epilogue: v = (main + corr/2048) / (2^14 * l), written as hi/lo f16 planes
    // (register-only + global stores; last loop barrier protects LDS reuse)
    size_t obase = ((size_t)(b * 2048 + rowBase)) * 1024 + h * 128 + (lane & 15);
    #pragma unroll
    for (int r2 = 0; r2 < 4; ++r2) {
      float inv = 1.f / (lreg[r2] * 16384.0f);
      #pragma unroll
      for (int db = 0; db < 8; ++db) {
        float v = (om[db][r2] + oc[db][r2] * (1.0f / 2048.0f)) * inv;
        _Float16 hh, ll;
        split_f16(v, hh, ll);
        attn_h[obase + (size_t)r2 * 1024 + db * 16] = hh;
        attn_l[obase + (size_t)r2 * 1024 + db * 16] = ll;
      }
    }
  }
}

// ---------------- kernel 6: noisy top-k router ----------------
__global__ __launch_bounds__(256) void k_router(
    const float* __restrict__ xn, const float* __restrict__ Wr,
    const float* __restrict__ br, const float* __restrict__ Wn,
    const float* __restrict__ bn, float* __restrict__ rp_out,
    float* __restrict__ idx_out) {
  int wave = threadIdx.x >> 6, lane = threadIdx.x & 63;
  int r = blockIdx.x * 4 + wave;
  const float* xr = xn + (size_t)r * 1024;
  float acc[16];
  #pragma unroll
  for (int i = 0; i < 16; ++i) acc[i] = 0.f;
  int cbase = lane * 16;
  for (int cc = 0; cc < 16; ++cc) {
    int c = cbase + cc;
    float xv = xr[c];
    const float4* wr4 = (const float4*)(Wr + (size_t)c * 8);
    float4 w0 = wr4[0], w1 = wr4[1];
    acc[0] += xv * w0.x; acc[1] += xv * w0.y; acc[2] += xv * w0.z; acc[3] += xv * w0.w;
    acc[4] += xv * w1.x; acc[5] += xv * w1.y; acc[6] += xv * w1.z; acc[7] += xv * w1.w;
    const float4* wn4 = (const float4*)(Wn + (size_t)c * 8);
    float4 n0 = wn4[0], n1 = wn4[1];
    acc[8]  += xv * n0.x; acc[9]  += xv * n0.y; acc[10] += xv * n0.z; acc[11] += xv * n0.w;
    acc[12] += xv * n1.x; acc[13] += xv * n1.y; acc[14] += xv * n1.z; acc[15] += xv * n1.w;
  }
  #pragma unroll
  for (int i = 0; i < 16; ++i) {
    #pragma unroll
    for (int off = 32; off > 0; off >>= 1) acc[i] += __shfl_down(acc[i], off, 64);
  }
  if (lane == 0) {
    float noisy[8];
    uint32_t nbase = (uint32_t)r * 8u;
    #pragma unroll
    for (int e = 0; e < 8; ++e) {
      float lg = acc[e] + br[e];
      float x = acc[8 + e] + bn[e];
      float sp = __fadd_rn(fmaxf(x, 0.f), log1pf(expf(-fabsf(x))));
      float nz = jax_noise(nbase + (uint32_t)e);
      noisy[e] = __fadd_rn(lg, __fmul_rn(nz, sp));
    }
    float v1 = -INFINITY, v2 = -INFINITY;
    int i1 = 0, i2 = 0;
    #pragma unroll
    for (int e = 0; e < 8; ++e) {
      float vv = noisy[e];
      if (vv > v1) { v2 = v1; i2 = i1; v1 = vv; i1 = e; }
      else if (vv > v2) { v2 = vv; i2 = e; }
    }
    float e2 = expf(v2 - v1);
    float ssum = 1.f + e2;
    float p1 = 1.f / ssum, p2 = e2 / ssum;
    float rp[8];
    #pragma unroll
    for (int e = 0; e < 8; ++e) rp[e] = 0.f;
    rp[i1] = p1; rp[i2] = p2;
    float* op = rp_out + (size_t)r * 8;
    #pragma unroll
    for (int e = 0; e < 8; ++e) op[e] = rp[e];
    idx_out[(size_t)r * 2]     = (float)i1;
    idx_out[(size_t)r * 2 + 1] = (float)i2;
  }
}

// ---------------- launch ----------------
extern "C" void kernel_launch(void* const* d_in, const int* in_sizes, int n_in,
                              void* d_out, int out_size, void* d_ws, size_t ws_size,
                              hipStream_t stream) {
  const int*   idx = (const int*)d_in[0];
  const float* tok = (const float*)d_in[1];
  const float* pos = (const float*)d_in[2];
  const float* Wq  = (const float*)d_in[3];
  const float* Wk  = (const float*)d_in[4];
  const float* Wv  = (const float*)d_in[5];
  const float* Wo  = (const float*)d_in[6];
  const float* bo  = (const float*)d_in[7];
  const float* g1  = (const float*)d_in[8];
  const float* b1  = (const float*)d_in[9];
  const float* g2  = (const float*)d_in[10];
  const float* b2  = (const float*)d_in[11];
  const float* Wr  = (const float*)d_in[12];
  const float* br  = (const float*)d_in[13];
  const float* Wn  = (const float*)d_in[14];
  const float* bn  = (const float*)d_in[15];

  float* out_xnorm = (float*)d_out;             // 4*2048*1024
  float* out_rp    = out_xnorm + 8388608;       // 4*2048*8
  float* out_idx   = out_rp + 65536;            // 4*2048*2 (written as float)
  float* out_x     = out_idx + 16384;           // 4*2048*1024

  // workspace: 8 f16 planes x 16 MB = 128 MB
  _Float16* xnh  = (_Float16*)d_ws;
  _Float16* xnl  = xnh + 8388608;
  _Float16* qhp  = xnl + 8388608;
  _Float16* qlp  = qhp + 8388608;
  _Float16* khp  = qlp + 8388608;
  _Float16* klp  = khp + 8388608;
  _Float16* vthp = klp + 8388608;               // [bh][d][t]
  _Float16* vtlp = vthp + 8388608;
  // attn planes reuse xn planes (xn fully consumed by k_qkv)
  _Float16* attn_h = xnh;
  _Float16* attn_l = xnl;
  // weight hi/lo planes stashed in out_xnorm (16 MB of 32 MB);
  // fully overwritten later by k_ln2 after k_proj_res has consumed them.
  _Float16* wqt_h = (_Float16*)out_xnorm;       // 24*128*1024
  _Float16* wqt_l = wqt_h + 3145728;
  _Float16* wot_h = wqt_l + 3145728;            // 1024*1024
  _Float16* wot_l = wot_h + 1048576;

  k_wsplit<<<32, 128, 0, stream>>>(Wq, Wk, Wv, Wo, wqt_h, wqt_l, wot_h, wot_l);
  k_embed_ln1<<<8192, 256, 0, stream>>>(idx, tok, pos, g1, b1, out_x, xnh, xnl);
  k_qkv<<<dim3(24, 64), 256, 0, stream>>>(xnh, xnl, wqt_h, wqt_l,
                                          qhp, qlp, khp, klp, vthp, vtlp);
  k_attn<<<dim3(32, 8), 512, 0, stream>>>(qhp, qlp, khp, klp, vthp, vtlp,
                                          attn_h, attn_l);
  k_proj_res<<<dim3(8, 64), 256, 0, stream>>>(attn_h, attn_l, wot_h, wot_l, bo, out_x);
  k_ln2<<<8192, 256, 0, stream>>>(out_x, g2, b2, out_xnorm);
  k_router<<<2048, 256, 0, stream>>>(out_xnorm, Wr, br, Wn, bn, out_rp, out_idx);
}

// Round 9
// 958.043 us; speedup vs baseline: 1.1325x; 1.0099x over previous
//
#include <hip/hip_runtime.h>
#include <math.h>
#include <stdint.h>

typedef __attribute__((ext_vector_type(8))) _Float16 f16x8;  // 8 f16 = 4 VGPR
typedef __attribute__((ext_vector_type(4))) _Float16 f16x4;  // 8 bytes
typedef __attribute__((ext_vector_type(4))) float f32x4;

// Dekker-style split: x ~= hi + lo/2048, both f16, lo kept out of denormal range.
__device__ __forceinline__ void split_f16(float x, _Float16& h, _Float16& l) {
  h = (_Float16)x;
  l = (_Float16)((x - (float)h) * 2048.0f);
}

__device__ __forceinline__ void gld16(const void* g, void* l) {
  __builtin_amdgcn_global_load_lds(
      (const __attribute__((address_space(1))) void*)g,
      (__attribute__((address_space(3))) void*)l, 16, 0, 0);
}

// ---------------- JAX threefry2x32 (key = [0,42]) + normal transform ----------------
__device__ __forceinline__ void threefry2x32_42(uint32_t x0, uint32_t x1,
                                                uint32_t& o0, uint32_t& o1) {
  const uint32_t k0 = 0u, k1 = 42u;
  const uint32_t k2 = k0 ^ k1 ^ 0x1BD11BDAu;
  x0 += k0; x1 += k1;
#define TF_R(r) { x0 += x1; x1 = (x1 << (r)) | (x1 >> (32 - (r))); x1 ^= x0; }
  TF_R(13) TF_R(15) TF_R(26) TF_R(6)
  x0 += k1; x1 += k2 + 1u;
  TF_R(17) TF_R(29) TF_R(16) TF_R(24)
  x0 += k2; x1 += k0 + 2u;
  TF_R(13) TF_R(15) TF_R(26) TF_R(6)
  x0 += k0; x1 += k1 + 3u;
  TF_R(17) TF_R(29) TF_R(16) TF_R(24)
  x0 += k1; x1 += k2 + 4u;
  TF_R(13) TF_R(15) TF_R(26) TF_R(6)
  x0 += k2; x1 += k0 + 5u;
#undef TF_R
  o0 = x0; o1 = x1;
}

__device__ __forceinline__ float jax_erfinv_f32(float x) {
  float xx = __fmul_rn(x, x);
  float w = -log1pf(-xx);
  float p;
  if (w < 5.0f) {
    w = __fadd_rn(w, -2.5f);
    p = 2.81022636e-08f;
    p = __fadd_rn(3.43273939e-07f, __fmul_rn(p, w));
    p = __fadd_rn(-3.5233877e-06f, __fmul_rn(p, w));
    p = __fadd_rn(-4.39150654e-06f, __fmul_rn(p, w));
    p = __fadd_rn(0.00021858087f, __fmul_rn(p, w));
    p = __fadd_rn(-0.00125372503f, __fmul_rn(p, w));
    p = __fadd_rn(-0.00417768164f, __fmul_rn(p, w));
    p = __fadd_rn(0.246640727f, __fmul_rn(p, w));
    p = __fadd_rn(1.50140941f, __fmul_rn(p, w));
  } else {
    w = __fadd_rn(sqrtf(w), -3.0f);
    p = -0.000200214257f;
    p = __fadd_rn(0.000100950558f, __fmul_rn(p, w));
    p = __fadd_rn(0.00134934322f, __fmul_rn(p, w));
    p = __fadd_rn(-0.00367342844f, __fmul_rn(p, w));
    p = __fadd_rn(0.00573950773f, __fmul_rn(p, w));
    p = __fadd_rn(-0.0076224613f, __fmul_rn(p, w));
    p = __fadd_rn(0.00943887047f, __fmul_rn(p, w));
    p = __fadd_rn(1.00167406f, __fmul_rn(p, w));
    p = __fadd_rn(2.83297682f, __fmul_rn(p, w));
  }
  return __fmul_rn(p, x);
}

__device__ __forceinline__ float jax_noise(uint32_t n) {
  uint32_t o0, o1;
  threefry2x32_42(0u, n, o0, o1);
  uint32_t bits = o0 ^ o1;
  uint32_t fb = (bits >> 9) | 0x3F800000u;
  float f = __fadd_rn(__uint_as_float(fb), -1.0f);
  const float lo = __uint_as_float(0xBF7FFFFFu);
  float u = __fadd_rn(__fmul_rn(f, 2.0f), lo);
  u = fmaxf(lo, u);
  return __fmul_rn(__uint_as_float(0x3FB504F3u), jax_erfinv_f32(u));
}

// ---------------- block reduction helper (256 threads = 4 waves) ----------------
__device__ __forceinline__ float block_sum_256(float v, float* buf) {
  #pragma unroll
  for (int off = 32; off > 0; off >>= 1) v += __shfl_down(v, off, 64);
  int lane = threadIdx.x & 63;
  int w = threadIdx.x >> 6;
  if (lane == 0) buf[w] = v;
  __syncthreads();
  return buf[0] + buf[1] + buf[2] + buf[3];
}

// ---------------- kernel 0: weight transpose + split ----------------
__global__ __launch_bounds__(128) void k_wsplit(
    const float* __restrict__ Wq, const float* __restrict__ Wk,
    const float* __restrict__ Wv, const float* __restrict__ Wo,
    _Float16* __restrict__ wqt_h, _Float16* __restrict__ wqt_l,
    _Float16* __restrict__ wot_h, _Float16* __restrict__ wot_l) {
  int z = blockIdx.x, tid = threadIdx.x;
  const float* src;
  int ldn, n;
  _Float16 *dh, *dl;
  if (z < 24) {
    int which = z >> 3, h = z & 7;
    src = ((which == 0) ? Wq : (which == 1) ? Wk : Wv) + (size_t)h * 1024 * 128;
    ldn = 128; n = tid;
    dh = wqt_h + (size_t)z * 128 * 1024 + (size_t)n * 1024;
    dl = wqt_l + (size_t)z * 128 * 1024 + (size_t)n * 1024;
  } else {
    int zz = z - 24;
    src = Wo; ldn = 1024; n = zz * 128 + tid;
    dh = wot_h + (size_t)n * 1024;
    dl = wot_l + (size_t)n * 1024;
  }
  for (int k0 = 0; k0 < 1024; k0 += 16) {
    f16x8 hv0, hv1, lv0, lv1;
    #pragma unroll
    for (int j = 0; j < 8; ++j) {
      _Float16 hh, ll;
      split_f16(src[(size_t)(k0 + j) * ldn + n], hh, ll);
      hv0[j] = hh; lv0[j] = ll;
    }
    #pragma unroll
    for (int j = 0; j < 8; ++j) {
      _Float16 hh, ll;
      split_f16(src[(size_t)(k0 + 8 + j) * ldn + n], hh, ll);
      hv1[j] = hh; lv1[j] = ll;
    }
    *(f16x8*)(dh + k0) = hv0; *(f16x8*)(dh + k0 + 8) = hv1;
    *(f16x8*)(dl + k0) = lv0; *(f16x8*)(dl + k0 + 8) = lv1;
  }
}

// ---------------- kernel 1: embed + LN1 (xn written as hi/lo f16 planes) ----------------
__global__ __launch_bounds__(256) void k_embed_ln1(
    const int* __restrict__ idx, const float* __restrict__ tok,
    const float* __restrict__ pos, const float* __restrict__ g1,
    const float* __restrict__ b1, float* __restrict__ x_out,
    _Float16* __restrict__ xnh, _Float16* __restrict__ xnl) {
  __shared__ float bufA[4], bufB[4];
  int r = blockIdx.x;
  int t = r & 2047;
  int token = idx[r];
  int c4 = threadIdx.x;
  float4 tv = *((const float4*)(tok + (size_t)token * 1024) + c4);
  float4 pv = *((const float4*)(pos + (size_t)t * 1024) + c4);
  float4 xv = make_float4(tv.x + pv.x, tv.y + pv.y, tv.z + pv.z, tv.w + pv.w);
  *((float4*)(x_out + (size_t)r * 1024) + c4) = xv;
  float mu = block_sum_256(xv.x + xv.y + xv.z + xv.w, bufA) * (1.0f / 1024.0f);
  float d0 = xv.x - mu, d1 = xv.y - mu, d2 = xv.z - mu, d3 = xv.w - mu;
  float var = block_sum_256(d0*d0 + d1*d1 + d2*d2 + d3*d3, bufB) * (1.0f / 1024.0f);
  float rs = rsqrtf(var + 1e-5f);
  float4 gv = *((const float4*)g1 + c4);
  float4 bv = *((const float4*)b1 + c4);
  float xn0 = d0*rs*gv.x + bv.x, xn1 = d1*rs*gv.y + bv.y;
  float xn2 = d2*rs*gv.z + bv.z, xn3 = d3*rs*gv.w + bv.w;
  f16x4 hv, lv;
  _Float16 hh, ll;
  split_f16(xn0, hh, ll); hv[0] = hh; lv[0] = ll;
  split_f16(xn1, hh, ll); hv[1] = hh; lv[1] = ll;
  split_f16(xn2, hh, ll); hv[2] = hh; lv[2] = ll;
  split_f16(xn3, hh, ll); hv[3] = hh; lv[3] = ll;
  *(f16x4*)(xnh + (size_t)r * 1024 + c4 * 4) = hv;
  *(f16x4*)(xnl + (size_t)r * 1024 + c4 * 4) = lv;
}

// ---------------- kernel 5: LN2 ----------------
__global__ __launch_bounds__(256) void k_ln2(
    const float* __restrict__ x, const float* __restrict__ g2,
    const float* __restrict__ b2, float* __restrict__ xn_out) {
  __shared__ float bufA[4], bufB[4];
  int r = blockIdx.x;
  int c4 = threadIdx.x;
  float4 xv = *((const float4*)(x + (size_t)r * 1024) + c4);
  float mu = block_sum_256(xv.x + xv.y + xv.z + xv.w, bufA) * (1.0f / 1024.0f);
  float d0 = xv.x - mu, d1 = xv.y - mu, d2 = xv.z - mu, d3 = xv.w - mu;
  float var = block_sum_256(d0*d0 + d1*d1 + d2*d2 + d3*d3, bufB) * (1.0f / 1024.0f);
  float rs = rsqrtf(var + 1e-5f);
  float4 gv = *((const float4*)g2 + c4);
  float4 bv = *((const float4*)b2 + c4);
  float4 xn = make_float4(d0*rs*gv.x + bv.x, d1*rs*gv.y + bv.y,
                          d2*rs*gv.z + bv.z, d3*rs*gv.w + bv.w);
  *((float4*)(xn_out + (size_t)r * 1024) + c4) = xn;
}

// ---------------- kernel 2: QKV projection, double-f16 MFMA GEMM ----------------
// KSTEP=32, DOUBLE-BUFFERED (LDS 64KB; VGPR=196 caps at 2 blocks/CU anyway, so
// dbuf is free). stage(next) issued before compute(cur); one barrier per K-step.
__global__ __launch_bounds__(256) void k_qkv(
    const _Float16* __restrict__ xnh, const _Float16* __restrict__ xnl,
    const _Float16* __restrict__ wth, const _Float16* __restrict__ wtl,
    _Float16* __restrict__ qh, _Float16* __restrict__ ql,
    _Float16* __restrict__ kh, _Float16* __restrict__ kl,
    _Float16* __restrict__ vth, _Float16* __restrict__ vtl) {
  __shared__ __align__(16) _Float16 Ah[2][128 * 32], Al[2][128 * 32];  // 32 KB
  __shared__ __align__(16) _Float16 Bh[2][128 * 32], Bl[2][128 * 32];  // 32 KB
  int z = blockIdx.x;
  int which = z >> 3, h = z & 7;
  int m0 = blockIdx.y * 128;
  int tid = threadIdx.x, w = tid >> 6, lane = tid & 63;
  const _Float16* bsh = wth + (size_t)z * 128 * 1024;
  const _Float16* bsl = wtl + (size_t)z * 128 * 1024;
  f32x4 om[2][8], oc[2][8];
  const f32x4 zero4 = {0.f, 0.f, 0.f, 0.f};
  #pragma unroll
  for (int mr = 0; mr < 2; ++mr)
    #pragma unroll
    for (int nb = 0; nb < 8; ++nb) { om[mr][nb] = zero4; oc[mr][nb] = zero4; }

  // wave w stages rows w*32..w*32+31 of A and B tiles (16 rows / inst)
  auto stage = [&](int cur, int k0) {
    #pragma unroll
    for (int i2 = 0; i2 < 2; ++i2) {
      int r = w * 32 + i2 * 16 + (lane >> 2);
      int gs = (lane & 3) ^ ((r >> 1) & 3);
      size_t ao = (size_t)(m0 + r) * 1024 + k0 + gs * 8;
      size_t bo_ = (size_t)r * 1024 + k0 + gs * 8;
      gld16(xnh + ao, &Ah[cur][(w * 32 + i2 * 16) * 32]);
      gld16(xnl + ao, &Al[cur][(w * 32 + i2 * 16) * 32]);
      gld16(bsh + bo_, &Bh[cur][(w * 32 + i2 * 16) * 32]);
      gld16(bsl + bo_, &Bl[cur][(w * 32 + i2 * 16) * 32]);
    }
  };

  stage(0, 0);
  asm volatile("s_waitcnt vmcnt(0)" ::: "memory");
  __syncthreads();
  int cur = 0;

  for (int k0 = 0; k0 < 1024; k0 += 32) {
    if (k0 + 32 < 1024) stage(cur ^ 1, k0 + 32);  // prefetch in flight
    f16x8 ah[2], al[2];
    #pragma unroll
    for (int mr = 0; mr < 2; ++mr) {
      int arow = w * 32 + mr * 16 + (lane & 15);
      int ag = (lane >> 4) ^ ((arow >> 1) & 3);
      ah[mr] = *(f16x8*)&Ah[cur][arow * 32 + ag * 8];
      al[mr] = *(f16x8*)&Al[cur][arow * 32 + ag * 8];
    }
    #pragma unroll
    for (int nb = 0; nb < 8; ++nb) {
      int brow = nb * 16 + (lane & 15);
      int bg = (lane >> 4) ^ ((brow >> 1) & 3);
      f16x8 b8h = *(f16x8*)&Bh[cur][brow * 32 + bg * 8];
      f16x8 b8l = *(f16x8*)&Bl[cur][brow * 32 + bg * 8];
      #pragma unroll
      for (int mr = 0; mr < 2; ++mr) {
        om[mr][nb] = __builtin_amdgcn_mfma_f32_16x16x32_f16(ah[mr], b8h, om[mr][nb], 0, 0, 0);
        oc[mr][nb] = __builtin_amdgcn_mfma_f32_16x16x32_f16(ah[mr], b8l, oc[mr][nb], 0, 0, 0);
        oc[mr][nb] = __builtin_amdgcn_mfma_f32_16x16x32_f16(al[mr], b8h, oc[mr][nb], 0, 0, 0);
      }
    }
    asm volatile("s_waitcnt vmcnt(0)" ::: "memory");  // prefetched loads done
    __syncthreads();                                   // all waves done with cur
    cur ^= 1;
  }
  // epilogue: D col = lane&15 (n), row = (lane>>4)*4 + r2 (m)
  int bb = m0 >> 11, tb = m0 & 2047;
  if (which < 2) {
    _Float16* OH = (which == 0) ? qh : kh;
    _Float16* OL = (which == 0) ? ql : kl;
    size_t base = (size_t)(bb * 8 + h) * 2048 * 128;
    #pragma unroll
    for (int mr = 0; mr < 2; ++mr)
      #pragma unroll
      for (int r2 = 0; r2 < 4; ++r2) {
        int t = tb + w * 32 + mr * 16 + ((lane >> 4) << 2) + r2;
        size_t roff = base + (size_t)t * 128 + (lane & 15);
        #pragma unroll
        for (int nb = 0; nb < 8; ++nb) {
          float v = om[mr][nb][r2] + oc[mr][nb][r2] * (1.0f / 2048.0f);
          _Float16 hh, ll;
          split_f16(v, hh, ll);
          OH[roff + nb * 16] = hh;
          OL[roff + nb * 16] = ll;
        }
      }
  } else {
    size_t base = (size_t)(bb * 8 + h) * 128 * 2048;
    #pragma unroll
    for (int mr = 0; mr < 2; ++mr) {
      int t4 = tb + w * 32 + mr * 16 + ((lane >> 4) << 2);
      #pragma unroll
      for (int nb = 0; nb < 8; ++nb) {
        int col = nb * 16 + (lane & 15);
        size_t off = base + (size_t)col * 2048 + t4;
        f16x4 hv, lv;
        #pragma unroll
        for (int r2 = 0; r2 < 4; ++r2) {
          _Float16 hh, ll;
          split_f16(om[mr][nb][r2] + oc[mr][nb][r2] * (1.0f / 2048.0f), hh, ll);
          hv[r2] = hh; lv[r2] = ll;
        }
        *(f16x4*)(vth + off) = hv;
        *(f16x4*)(vtl + off) = lv;
      }
    }
  }
}

// ---------------- kernel 4: x += attn @ Wo + bo, double-f16 MFMA ----------------
// KSTEP 64->32 + double-buffer (LDS 64KB). Same pipeline as k_qkv; K-accumulation
// order unchanged (32-wide MFMA sequence identical) -> bit-identical result.
__global__ __launch_bounds__(256) void k_proj_res(
    const _Float16* __restrict__ ah_, const _Float16* __restrict__ al_,
    const _Float16* __restrict__ wth, const _Float16* __restrict__ wtl,
    const float* __restrict__ bo, float* __restrict__ x_io) {
  __shared__ __align__(16) _Float16 Ah[2][128 * 32], Al[2][128 * 32];
  __shared__ __align__(16) _Float16 Bh[2][128 * 32], Bl[2][128 * 32];
  int n0 = blockIdx.x * 128;
  int m0 = blockIdx.y * 128;
  int tid = threadIdx.x, w = tid >> 6, lane = tid & 63;
  f32x4 om[2][8], oc[2][8];
  const f32x4 zero4 = {0.f, 0.f, 0.f, 0.f};
  #pragma unroll
  for (int mr = 0; mr < 2; ++mr)
    #pragma unroll
    for (int nb = 0; nb < 8; ++nb) { om[mr][nb] = zero4; oc[mr][nb] = zero4; }

  auto stage = [&](int cur, int k0) {
    #pragma unroll
    for (int i2 = 0; i2 < 2; ++i2) {
      int r = w * 32 + i2 * 16 + (lane >> 2);
      int gs = (lane & 3) ^ ((r >> 1) & 3);
      size_t ao = (size_t)(m0 + r) * 1024 + k0 + gs * 8;
      size_t bo_ = (size_t)(n0 + r) * 1024 + k0 + gs * 8;
      gld16(ah_ + ao, &Ah[cur][(w * 32 + i2 * 16) * 32]);
      gld16(al_ + ao, &Al[cur][(w * 32 + i2 * 16) * 32]);
      gld16(wth + bo_, &Bh[cur][(w * 32 + i2 * 16) * 32]);
      gld16(wtl + bo_, &Bl[cur][(w * 32 + i2 * 16) * 32]);
    }
  };

  stage(0, 0);
  asm volatile("s_waitcnt vmcnt(0)" ::: "memory");
  __syncthreads();
  int cur = 0;

  for (int k0 = 0; k0 < 1024; k0 += 32) {
    if (k0 + 32 < 1024) stage(cur ^ 1, k0 + 32);
    f16x8 ah[2], al[2];
    #pragma unroll
    for (int mr = 0; mr < 2; ++mr) {
      int arow = w * 32 + mr * 16 + (lane & 15);
      int ag = (lane >> 4) ^ ((arow >> 1) & 3);
      ah[mr] = *(f16x8*)&Ah[cur][arow * 32 + ag * 8];
      al[mr] = *(f16x8*)&Al[cur][arow * 32 + ag * 8];
    }
    #pragma unroll
    for (int nb = 0; nb < 8; ++nb) {
      int brow = nb * 16 + (lane & 15);
      int bg = (lane >> 4) ^ ((brow >> 1) & 3);
      f16x8 b8h = *(f16x8*)&Bh[cur][brow * 32 + bg * 8];
      f16x8 b8l = *(f16x8*)&Bl[cur][brow * 32 + bg * 8];
      #pragma unroll
      for (int mr = 0; mr < 2; ++mr) {
        om[mr][nb] = __builtin_amdgcn_mfma_f32_16x16x32_f16(ah[mr], b8h, om[mr][nb], 0, 0, 0);
        oc[mr][nb] = __builtin_amdgcn_mfma_f32_16x16x32_f16(ah[mr], b8l, oc[mr][nb], 0, 0, 0);
        oc[mr][nb] = __builtin_amdgcn_mfma_f32_16x16x32_f16(al[mr], b8h, oc[mr][nb], 0, 0, 0);
      }
    }
    asm volatile("s_waitcnt vmcnt(0)" ::: "memory");
    __syncthreads();
    cur ^= 1;
  }
  #pragma unroll
  for (int mr = 0; mr < 2; ++mr)
    #pragma unroll
    for (int nb = 0; nb < 8; ++nb) {
      int col = n0 + nb * 16 + (lane & 15);
      float bov = bo[col];
      #pragma unroll
      for (int r2 = 0; r2 < 4; ++r2) {
        int gm = m0 + w * 32 + mr * 16 + ((lane >> 4) << 2) + r2;
        float* p = x_io + (size_t)gm * 1024 + col;
        *p += om[mr][nb][r2] + oc[mr][nb][r2] * (1.0f / 2048.0f) + bov;
      }
    }
}

// ---------------- kernel 3: causal flash attention, double-f16 MFMA ----------------
// 8-wave blocks (512 thr), Q-tile = 128 rows (wave w: rows 16w..16w+15).
// In-block pairing qt in {qs, 15-qs}: grid 256 = 1 block/CU, uniform 68 KV-tiles.
// KVBLK=32 double-buffered; LDS 80KB; 2 waves/SIMD.
// Grid (x = b*8+h, y = qs) so a head's 8 blocks share id%8 -> same XCD L2.
__global__ __launch_bounds__(512) void k_attn(
    const _Float16* __restrict__ qhp, const _Float16* __restrict__ qlp,
    const _Float16* __restrict__ khp, const _Float16* __restrict__ klp,
    const _Float16* __restrict__ vthp, const _Float16* __restrict__ vtlp,
    _Float16* __restrict__ attn_h, _Float16* __restrict__ attn_l) {
  __shared__ __align__(16) _Float16 Ksh[2][32 * 128];  // 16 KB
  __shared__ __align__(16) _Float16 Ksl[2][32 * 128];  // 16 KB
  __shared__ __align__(16) _Float16 Vh[2][128 * 32];   // 16 KB
  __shared__ __align__(16) _Float16 Vl[2][128 * 32];   // 16 KB
  __shared__ __align__(16) _Float16 Ph8[8][16 * 32];   // 8 KB
  __shared__ __align__(16) _Float16 Pl8[8][16 * 32];   // 8 KB

  int bh_ = blockIdx.x;            // b*8 + h
  int b = bh_ >> 3, h = bh_ & 7;
  int qs = blockIdx.y;             // 0..7; pair (qs, 15-qs)
  int tid = threadIdx.x;
  int w = tid >> 6, lane = tid & 63;

  size_t bh = (size_t)(b * 8 + h) * 2048 * 128;
  const _Float16* qhb = qhp + bh;
  const _Float16* qlb = qlp + bh;
  const _Float16* khb = khp + bh;
  const _Float16* klb = klp + bh;
  const _Float16* vhb = vthp + bh;   // [d][t]
  const _Float16* vlb = vtlp + bh;
  _Float16* Ph = &Ph8[w][0];
  _Float16* Pl = &Pl8[w][0];

  const f32x4 zero4 = {0.f, 0.f, 0.f, 0.f};

  // per wave per tile: 2 K gld16 (hi/lo, rows 4w..4w+3) + 2 V gld16 (rows 16w..16w+15)
  auto stage = [&](int cur, int j0) {
    int kr = (w << 2) + (lane >> 4);
    int kg = (lane & 15) ^ (kr & 7);
    size_t kgo = (size_t)(j0 + kr) * 128 + kg * 8;
    gld16(khb + kgo, &Ksh[cur][(w << 2) * 128]);
    gld16(klb + kgo, &Ksl[cur][(w << 2) * 128]);
    int vr = (w << 4) + (lane >> 2);
    int vg = (lane & 3) ^ ((vr >> 1) & 3);
    size_t vgo = (size_t)vr * 2048 + j0 + vg * 8;
    gld16(vhb + vgo, &Vh[cur][(w << 4) * 32]);
    gld16(vlb + vgo, &Vl[cur][(w << 4) * 32]);
  };

  #pragma unroll 1
  for (int pi = 0; pi < 2; ++pi) {
    int qt = pi ? (15 - qs) : qs;
    int t0 = qt << 7;                  // 128-row Q-tile
    int tW = t0 + w * 16;
    int rowBase = tW + ((lane >> 4) << 2);

    // Q fragments: lane l -> row l&15, d = kk*32 + (l>>4)*8 ..
    size_t qoff = (size_t)(tW + (lane & 15)) * 128 + ((lane >> 4) << 3);
    f16x8 qfh[4], qfl[4];
    #pragma unroll
    for (int kk = 0; kk < 4; ++kk) {
      qfh[kk] = *(const f16x8*)(qhb + qoff + kk * 32);
      qfl[kk] = *(const f16x8*)(qlb + qoff + kk * 32);
    }

    f32x4 om[8], oc[8];
    #pragma unroll
    for (int db = 0; db < 8; ++db) { om[db] = zero4; oc[db] = zero4; }
    float mreg[4], lreg[4];
    #pragma unroll
    for (int r2 = 0; r2 < 4; ++r2) { mreg[r2] = -INFINITY; lreg[r2] = 0.f; }

    int nt = 4 * qt + 4;   // KV tiles of 32 covering rows 0..t0+127
    stage(0, 0);
    asm volatile("s_waitcnt vmcnt(0)" ::: "memory");
    __syncthreads();
    int cur = 0;

    #pragma unroll 1
    for (int t = 0; t < nt; ++t) {
      if (t + 1 < nt) stage(cur ^ 1, (t + 1) * 32);  // prefetch in flight
      int j0 = t * 32;

      // ---- QK^T: S[16 q][32 kv]; main + corr accumulators ----
      f32x4 sm[2], sc[2];
      #pragma unroll
      for (int nb = 0; nb < 2; ++nb) { sm[nb] = zero4; sc[nb] = zero4; }
      #pragma unroll
      for (int kk = 0; kk < 4; ++kk) {
        #pragma unroll
        for (int nb = 0; nb < 2; ++nb) {
          int krow = nb * 16 + (lane & 15);
          int kg = (kk * 4 + (lane >> 4)) ^ (krow & 7);
          f16x8 kfh = *(f16x8*)&Ksh[cur][krow * 128 + kg * 8];
          f16x8 kfl = *(f16x8*)&Ksl[cur][krow * 128 + kg * 8];
          sm[nb] = __builtin_amdgcn_mfma_f32_16x16x32_f16(qfh[kk], kfh, sm[nb], 0, 0, 0);
          sc[nb] = __builtin_amdgcn_mfma_f32_16x16x32_f16(qfh[kk], kfl, sc[nb], 0, 0, 0);
          sc[nb] = __builtin_amdgcn_mfma_f32_16x16x32_f16(qfl[kk], kfh, sc[nb], 0, 0, 0);
        }
      }

      // ---- scale + causal mask + online softmax ----
      float rmax[4];
      #pragma unroll
      for (int r2 = 0; r2 < 4; ++r2) rmax[r2] = -INFINITY;
      #pragma unroll
      for (int nb = 0; nb < 2; ++nb) {
        int col = j0 + nb * 16 + (lane & 15);
        #pragma unroll
        for (int r2 = 0; r2 < 4; ++r2) {
          float sv = (sm[nb][r2] + sc[nb][r2] * (1.0f / 2048.0f)) * 0.03125f;
          sv = (col > rowBase + r2) ? -INFINITY : sv;
          sm[nb][r2] = sv;
          rmax[r2] = fmaxf(rmax[r2], sv);
        }
      }
      #pragma unroll
      for (int mk = 1; mk < 16; mk <<= 1)
        #pragma unroll
        for (int r2 = 0; r2 < 4; ++r2)
          rmax[r2] = fmaxf(rmax[r2], __shfl_xor(rmax[r2], mk, 64));
      float alpha[4], rsum[4];
      bool newmax = false;
      #pragma unroll
      for (int r2 = 0; r2 < 4; ++r2) {
        float mnew = fmaxf(mreg[r2], rmax[r2]);
        newmax |= (mnew > mreg[r2]);
        alpha[r2] = __expf(mreg[r2] - mnew);
        mreg[r2] = mnew;
        rsum[r2] = 0.f;
      }
      #pragma unroll
      for (int nb = 0; nb < 2; ++nb)
        #pragma unroll
        for (int r2 = 0; r2 < 4; ++r2) {
          float p = __expf(sm[nb][r2] - mreg[r2]);
          sm[nb][r2] = p;
          rsum[r2] += p;
        }
      #pragma unroll
      for (int mk = 1; mk < 16; mk <<= 1)
        #pragma unroll
        for (int r2 = 0; r2 < 4; ++r2)
          rsum[r2] += __shfl_xor(rsum[r2], mk, 64);
      #pragma unroll
      for (int r2 = 0; r2 < 4; ++r2)
        lreg[r2] = lreg[r2] * alpha[r2] + rsum[r2];

      // ---- P*2^14 -> hi/lo planes in per-wave LDS (granule-XOR swizzle) ----
      #pragma unroll
      for (int nb = 0; nb < 2; ++nb) {
        int col = nb * 16 + (lane & 15);
        #pragma unroll
        for (int r2 = 0; r2 < 4; ++r2) {
          int prow = ((lane >> 4) << 2) + r2;
          int sg = (col >> 3) ^ ((prow >> 1) & 3);
          float ps = sm[nb][r2] * 16384.0f;
          _Float16 hh, ll;
          split_f16(ps, hh, ll);
          Ph[prow * 32 + sg * 8 + (col & 7)] = hh;
          Pl[prow * 32 + sg * 8 + (col & 7)] = ll;
        }
      }

      // ---- rescale O (skipped when no lane saw a new row-max: alpha == 1) ----
      if (__any((int)newmax)) {
        #pragma unroll
        for (int db = 0; db < 8; ++db)
          #pragma unroll
          for (int r2 = 0; r2 < 4; ++r2) {
            om[db][r2] *= alpha[r2];
            oc[db][r2] *= alpha[r2];
          }
      }

      // ---- PV: O[16 q][128 d] += P[16][32] * V[32][128] ----
      {
        int prow = lane & 15;
        int pg = (lane >> 4) ^ ((prow >> 1) & 3);
        f16x8 pah = *(f16x8*)&Ph[prow * 32 + pg * 8];
        f16x8 pal = *(f16x8*)&Pl[prow * 32 + pg * 8];
        #pragma unroll
        for (int db = 0; db < 8; ++db) {
          int vrow = db * 16 + (lane & 15);
          int vg = (lane >> 4) ^ ((vrow >> 1) & 3);
          f16x8 vfh = *(f16x8*)&Vh[cur][vrow * 32 + vg * 8];
          f16x8 vfl = *(f16x8*)&Vl[cur][vrow * 32 + vg * 8];
          om[db] = __builtin_amdgcn_mfma_f32_16x16x32_f16(pah, vfh, om[db], 0, 0, 0);
          oc[db] = __builtin_amdgcn_mfma_f32_16x16x32_f16(pah, vfl, oc[db], 0, 0, 0);
          oc[db] = __builtin_amdgcn_mfma_f32_16x16x32_f16(pal, vfh, oc[db], 0, 0, 0);
        }
      }

      asm volatile("s_waitcnt vmcnt(0)" ::: "memory");  // next tile's loads done
      __syncthreads();                                   // all waves done with cur
      cur ^= 1;
    }

    // epilogue: v = (main + corr/2048) / (2^14 * l), written as hi/lo f16 planes
    size_t obase = ((size_t)(b * 2048 + rowBase)) * 1024 + h * 128 + (lane & 15);
    #pragma unroll
    for (int r2 = 0; r2 < 4; ++r2) {
      float inv = 1.f / (lreg[r2] * 16384.0f);
      #pragma unroll
      for (int db = 0; db < 8; ++db) {
        float v = (om[db][r2] + oc[db][r2] * (1.0f / 2048.0f)) * inv;
        _Float16 hh, ll;
        split_f16(v, hh, ll);
        attn_h[obase + (size_t)r2 * 1024 + db * 16] = hh;
        attn_l[obase + (size_t)r2 * 1024 + db * 16] = ll;
      }
    }
  }
}

// ---------------- kernel 6: noisy top-k router ----------------
__global__ __launch_bounds__(256) void k_router(
    const float* __restrict__ xn, const float* __restrict__ Wr,
    const float* __restrict__ br, const float* __restrict__ Wn,
    const float* __restrict__ bn, float* __restrict__ rp_out,
    float* __restrict__ idx_out) {
  int wave = threadIdx.x >> 6, lane = threadIdx.x & 63;
  int r = blockIdx.x * 4 + wave;
  const float* xr = xn + (size_t)r * 1024;
  float acc[16];
  #pragma unroll
  for (int i = 0; i < 16; ++i) acc[i] = 0.f;
  int cbase = lane * 16;
  for (int cc = 0; cc < 16; ++cc) {
    int c = cbase + cc;
    float xv = xr[c];
    const float4* wr4 = (const float4*)(Wr + (size_t)c * 8);
    float4 w0 = wr4[0], w1 = wr4[1];
    acc[0] += xv * w0.x; acc[1] += xv * w0.y; acc[2] += xv * w0.z; acc[3] += xv * w0.w;
    acc[4] += xv * w1.x; acc[5] += xv * w1.y; acc[6] += xv * w1.z; acc[7] += xv * w1.w;
    const float4* wn4 = (const float4*)(Wn + (size_t)c * 8);
    float4 n0 = wn4[0], n1 = wn4[1];
    acc[8]  += xv * n0.x; acc[9]  += xv * n0.y; acc[10] += xv * n0.z; acc[11] += xv * n0.w;
    acc[12] += xv * n1.x; acc[13] += xv * n1.y; acc[14] += xv * n1.z; acc[15] += xv * n1.w;
  }
  #pragma unroll
  for (int i = 0; i < 16; ++i) {
    #pragma unroll
    for (int off = 32; off > 0; off >>= 1) acc[i] += __shfl_down(acc[i], off, 64);
  }
  if (lane == 0) {
    float noisy[8];
    uint32_t nbase = (uint32_t)r * 8u;
    #pragma unroll
    for (int e = 0; e < 8; ++e) {
      float lg = acc[e] + br[e];
      float x = acc[8 + e] + bn[e];
      float sp = __fadd_rn(fmaxf(x, 0.f), log1pf(expf(-fabsf(x))));
      float nz = jax_noise(nbase + (uint32_t)e);
      noisy[e] = __fadd_rn(lg, __fmul_rn(nz, sp));
    }
    float v1 = -INFINITY, v2 = -INFINITY;
    int i1 = 0, i2 = 0;
    #pragma unroll
    for (int e = 0; e < 8; ++e) {
      float vv = noisy[e];
      if (vv > v1) { v2 = v1; i2 = i1; v1 = vv; i1 = e; }
      else if (vv > v2) { v2 = vv; i2 = e; }
    }
    float e2 = expf(v2 - v1);
    float ssum = 1.f + e2;
    float p1 = 1.f / ssum, p2 = e2 / ssum;
    float rp[8];
    #pragma unroll
    for (int e = 0; e < 8; ++e) rp[e] = 0.f;
    rp[i1] = p1; rp[i2] = p2;
    float* op = rp_out + (size_t)r * 8;
    #pragma unroll
    for (int e = 0; e < 8; ++e) op[e] = rp[e];
    idx_out[(size_t)r * 2]     = (float)i1;
    idx_out[(size_t)r * 2 + 1] = (float)i2;
  }
}

// ---------------- launch ----------------
extern "C" void kernel_launch(void* const* d_in, const int* in_sizes, int n_in,
                              void* d_out, int out_size, void* d_ws, size_t ws_size,
                              hipStream_t stream) {
  const int*   idx = (const int*)d_in[0];
  const float* tok = (const float*)d_in[1];
  const float* pos = (const float*)d_in[2];
  const float* Wq  = (const float*)d_in[3];
  const float* Wk  = (const float*)d_in[4];
  const float* Wv  = (const float*)d_in[5];
  const float* Wo  = (const float*)d_in[6];
  const float* bo  = (const float*)d_in[7];
  const float* g1  = (const float*)d_in[8];
  const float* b1  = (const float*)d_in[9];
  const float* g2  = (const float*)d_in[10];
  const float* b2  = (const float*)d_in[11];
  const float* Wr  = (const float*)d_in[12];
  const float* br  = (const float*)d_in[13];
  const float* Wn  = (const float*)d_in[14];
  const float* bn  = (const float*)d_in[15];

  float* out_xnorm = (float*)d_out;             // 4*2048*1024
  float* out_rp    = out_xnorm + 8388608;       // 4*2048*8
  float* out_idx   = out_rp + 65536;            // 4*2048*2 (written as float)
  float* out_x     = out_idx + 16384;           // 4*2048*1024

  // workspace: 8 f16 planes x 16 MB = 128 MB
  _Float16* xnh  = (_Float16*)d_ws;
  _Float16* xnl  = xnh + 8388608;
  _Float16* qhp  = xnl + 8388608;
  _Float16* qlp  = qhp + 8388608;
  _Float16* khp  = qlp + 8388608;
  _Float16* klp  = khp + 8388608;
  _Float16* vthp = klp + 8388608;               // [bh][d][t]
  _Float16* vtlp = vthp + 8388608;
  // attn planes reuse xn planes (xn fully consumed by k_qkv)
  _Float16* attn_h = xnh;
  _Float16* attn_l = xnl;
  // weight hi/lo planes stashed in out_xnorm (16 MB of 32 MB);
  // fully overwritten later by k_ln2 after k_proj_res has consumed them.
  _Float16* wqt_h = (_Float16*)out_xnorm;       // 24*128*1024
  _Float16* wqt_l = wqt_h + 3145728;
  _Float16* wot_h = wqt_l + 3145728;            // 1024*1024
  _Float16* wot_l = wot_h + 1048576;

  k_wsplit<<<32, 128, 0, stream>>>(Wq, Wk, Wv, Wo, wqt_h, wqt_l, wot_h, wot_l);
  k_embed_ln1<<<8192, 256, 0, stream>>>(idx, tok, pos, g1, b1, out_x, xnh, xnl);
  k_qkv<<<dim3(24, 64), 256, 0, stream>>>(xnh, xnl, wqt_h, wqt_l,
                                          qhp, qlp, khp, klp, vthp, vtlp);
  k_attn<<<dim3(32, 8), 512, 0, stream>>>(qhp, qlp, khp, klp, vthp, vtlp,
                                          attn_h, attn_l);
  k_proj_res<<<dim3(8, 64), 256, 0, stream>>>(attn_h, attn_l, wot_h, wot_l, bo, out_x);
  k_ln2<<<8192, 256, 0, stream>>>(out_x, g2, b2, out_xnorm);
  k_router<<<2048, 256, 0, stream>>>(out_xnorm, Wr, br, Wn, bn, out_rp, out_idx);
}